// Round 14
// baseline (176.556 us; speedup 1.0000x reference)
//
#include <hip/hip_runtime.h>
#include <cstdint>
#include <cstddef>

// Problem constants (b=1)
#define LL 2048     // sequence length
#define DD 1024     // model dim
#define NH 16       // heads
#define DH 64       // head dim
#define RSEG 32     // LL/64 chunks

#define E2C 0.18033688f  // 0.125 * log2(e): exp(z/8) = exp2(z*E2C)

using u16 = unsigned short;
typedef __attribute__((ext_vector_type(8))) __bf16 bf16x8;
typedef __attribute__((ext_vector_type(4))) float f32x4;
typedef __attribute__((ext_vector_type(8))) u16 u16x8;
typedef __attribute__((ext_vector_type(4))) u16 u16x4;
typedef __attribute__((ext_vector_type(4))) float f32x4v;

static __device__ __forceinline__ u16 f2bf(float f) {
  union { float f; unsigned u; } a; a.f = f;
  unsigned u = a.u;
  return (u16)((u + 0x7fffu + ((u >> 16) & 1u)) >> 16);
}
static __device__ __forceinline__ float bf2f(u16 x) {
  union { unsigned u; float f; } a; a.u = ((unsigned)x) << 16;
  return a.f;
}

static __device__ __forceinline__ f32x4 mfma16(bf16x8 a, bf16x8 b, f32x4 c) {
  return __builtin_amdgcn_mfma_f32_16x16x32_bf16(a, b, c, 0, 0, 0);
}

#define GLOAD_LDS16(gsrc, ldst)                                                        \
  __builtin_amdgcn_global_load_lds((const __attribute__((address_space(1))) void*)(gsrc), \
                                   (__attribute__((address_space(3))) void*)(ldst), 16, 0, 0)

// Stage a 64x64 bf16 tile from row-major global (row stride rs elems) into MFMA
// layout: byte = rb*2048 + kh*1024 + kg*256 + lr*16
static __device__ __forceinline__ void stage64(const u16* g, int rs, u16* lds, int wave, int lane) {
  int lr = lane & 15, kg = lane >> 4;
#pragma unroll
  for (int i = 0; i < 2; ++i) {
    int idx = wave * 2 + i;
    int rb = idx >> 1, kh = idx & 1;
    const u16* src = g + (size_t)(rb * 16 + lr) * rs + kh * 32 + kg * 8;
    GLOAD_LDS16(src, (char*)lds + idx * 1024);
  }
}

// Read one 16x32 A/B fragment from LDS-staged tile
static __device__ __forceinline__ bf16x8 frag64(const u16* lds, int rb, int t, int lane) {
  return *(const bf16x8*)((const char*)lds + rb * 2048 + t * 1024 + (lane >> 4) * 256 +
                          (lane & 15) * 16);
}

// Direct global fragment load (rows row.., k-slice koff..): matches 16x16x32 A/B layout
static __device__ __forceinline__ bf16x8 gfrag(const u16* g, int row, int rs, int koff) {
  return *(const bf16x8*)(g + (size_t)row * rs + koff);
}

// ---------------- fused fp32 -> bf16 cast of all inputs ----------------
__global__ __launch_bounds__(256) void k_castall(const float* __restrict__ hs,
                                                 const float* __restrict__ Wq,
                                                 const float* __restrict__ Wk,
                                                 const float* __restrict__ Wv,
                                                 const float* __restrict__ Wc,
                                                 u16* __restrict__ hs_bf, u16* __restrict__ wq_bf,
                                                 u16* __restrict__ wc_bf) {
  int i = (blockIdx.x * 256 + threadIdx.x) * 4;  // over 6M elements
  const float* src;
  u16* dst;
  int off;
  if (i < 2097152) { src = hs; dst = hs_bf; off = i; }
  else if (i < 3145728) { src = Wq; dst = wq_bf; off = i - 2097152; }
  else if (i < 4194304) { src = Wk; dst = wq_bf + 1048576; off = i - 3145728; }
  else if (i < 5242880) { src = Wv; dst = wq_bf + 2097152; off = i - 4194304; }
  else { src = Wc; dst = wc_bf; off = i - 5242880; }
  f32x4v v = *(const f32x4v*)(src + off);
  u16x4 o;
#pragma unroll
  for (int t = 0; t < 4; ++t) o[t] = f2bf(v[t]);
  *(u16x4*)(dst + off) = o;
}

// ---------------- GEMM: C[M,N] = A[M,K] * B[N,K]^T, dbuf BK=32 ----------------
template <int BM, int BN, bool WF32>
__global__ __launch_bounds__(256) void k_gemm(const u16* __restrict__ A, const u16* __restrict__ Ball,
                                              u16* __restrict__ Cb, float* __restrict__ Cf) {
  constexpr int FI = BM / 32, FJ = BN / 32;
  __shared__ u16 lA[2][BM * 32];
  __shared__ u16 lB[2][BN * 32];
  const int tid = threadIdx.x, lane = tid & 63, wave = tid >> 6;
  const int lr = lane & 15, kg = lane >> 4;
  const int wr = wave >> 1, wc = wave & 1;
  const u16* Bp = Ball + (size_t)blockIdx.z * (DD * DD);
  const int brow = blockIdx.y * BM, bcol = blockIdx.x * BN;
  f32x4 acc[FI][FJ] = {};

  auto stage = [&](int buf, int kt) {
#pragma unroll
    for (int i = 0; i < BM / 64; ++i) {
      int rb = wave * (BM / 64) + i;
      GLOAD_LDS16(A + (size_t)(brow + rb * 16 + lr) * DD + kt * 32 + kg * 8,
                  (char*)(&lA[buf][0]) + rb * 1024);
    }
#pragma unroll
    for (int i = 0; i < BN / 64; ++i) {
      int rb = wave * (BN / 64) + i;
      GLOAD_LDS16(Bp + (size_t)(bcol + rb * 16 + lr) * DD + kt * 32 + kg * 8,
                  (char*)(&lB[buf][0]) + rb * 1024);
    }
  };

  stage(0, 0);
  int cur = 0;
  for (int kt = 0; kt < DD / 32; ++kt) {
    __syncthreads();
    if (kt + 1 < DD / 32) stage(cur ^ 1, kt + 1);
    bf16x8 af[FI], bb[FJ];
#pragma unroll
    for (int f = 0; f < FI; ++f)
      af[f] = *(const bf16x8*)((const char*)(&lA[cur][0]) + (wr * FI + f) * 1024 + kg * 256 +
                               lr * 16);
#pragma unroll
    for (int f = 0; f < FJ; ++f)
      bb[f] = *(const bf16x8*)((const char*)(&lB[cur][0]) + (wc * FJ + f) * 1024 + kg * 256 +
                               lr * 16);
#pragma unroll
    for (int i = 0; i < FI; ++i)
#pragma unroll
      for (int j = 0; j < FJ; ++j) acc[i][j] = mfma16(af[i], bb[j], acc[i][j]);
    cur ^= 1;
  }
  u16* Co = Cb + (size_t)blockIdx.z * ((size_t)LL * DD);
#pragma unroll
  for (int i = 0; i < FI; ++i)
#pragma unroll
    for (int j = 0; j < FJ; ++j)
#pragma unroll
      for (int r = 0; r < 4; ++r) {
        int row = brow + (wr * FI + i) * 16 + kg * 4 + r;
        int col = bcol + (wc * FJ + j) * 16 + lr;
        if constexpr (WF32)
          Cf[(size_t)row * DD + col] = acc[i][j][r];
        else
          Co[(size_t)row * DD + col] = f2bf(acc[i][j][r]);
      }
}

// ---------------- score (blocks 0..511, c DESC) + transpose (512..1535), 512 thr ----------------
// score: c = 31-(x>>4), h = x&15 (stragglers first); 8 waves; wave w owns tiles j = w, w+8, ...
__global__ __launch_bounds__(512) void k_trsc(const u16* __restrict__ qb, const u16* __restrict__ kb,
                                              const u16* __restrict__ vb,
                                              const float* __restrict__ idx_dec,
                                              float* __restrict__ pcs, u16* __restrict__ kT,
                                              u16* __restrict__ vT) {
  __shared__ float dsum[8][64];
  __shared__ float invd_s[64];
  __shared__ u16 tile[64][72];
  const int tid = threadIdx.x;
  const int x = blockIdx.x;
  if (x < 512) {
    const int lane = tid & 63, wave = tid >> 6;
    const int lr = lane & 15, g = lane >> 4;
    const int c = 31 - (x >> 4), h = x & 15;
    bf16x8 aq[4][2];
#pragma unroll
    for (int fi = 0; fi < 4; ++fi)
#pragma unroll
      for (int t = 0; t < 2; ++t)
        aq[fi][t] = gfrag(qb, c * 64 + fi * 16 + lr, DD, h * DH + t * 32 + g * 8);

    // pass 1: row denominators
    float drow[4][4] = {};
    for (int j = wave; j <= c; j += 8) {
      bf16x8 bk[4][2];
#pragma unroll
      for (int fj = 0; fj < 4; ++fj)
#pragma unroll
        for (int t = 0; t < 2; ++t)
          bk[fj][t] = gfrag(kb, j * 64 + fj * 16 + lr, DD, h * DH + t * 32 + g * 8);
#pragma unroll
      for (int fi = 0; fi < 4; ++fi)
#pragma unroll
        for (int fj = 0; fj < 4; ++fj) {
          f32x4 z = {0.f, 0.f, 0.f, 0.f};
          z = mfma16(aq[fi][0], bk[fj][0], z);
          z = mfma16(aq[fi][1], bk[fj][1], z);
#pragma unroll
          for (int r = 0; r < 4; ++r) {
            float e = exp2f(z[r] * E2C);
            if (j == c && (fj * 16 + lr) > (fi * 16 + g * 4 + r)) e = 0.f;
            drow[fi][r] += e;
          }
        }
    }
#pragma unroll
    for (int fi = 0; fi < 4; ++fi)
#pragma unroll
      for (int r = 0; r < 4; ++r) {
        float s = drow[fi][r];
        s += __shfl_xor(s, 1, 64);
        s += __shfl_xor(s, 2, 64);
        s += __shfl_xor(s, 4, 64);
        s += __shfl_xor(s, 8, 64);
        drow[fi][r] = s;
      }
    if (lr == 0) {
#pragma unroll
      for (int fi = 0; fi < 4; ++fi)
#pragma unroll
        for (int r = 0; r < 4; ++r) dsum[wave][fi * 16 + g * 4 + r] = drow[fi][r];
    }
    __syncthreads();
    if (tid < 64) {
      float s = 0.f;
#pragma unroll
      for (int w2 = 0; w2 < 8; ++w2) s += dsum[w2][tid];
      invd_s[tid] = 1.f / s;
    }
    __syncthreads();
    float coef[4][4];
#pragma unroll
    for (int fi = 0; fi < 4; ++fi)
#pragma unroll
      for (int r = 0; r < 4; ++r) {
        int row = fi * 16 + g * 4 + r;
        coef[fi][r] = __expf(idx_dec[h * 64 + row]) * invd_s[row];
      }

    // pass 2: pcs columns
    for (int j = wave; j <= c; j += 8) {
      bf16x8 bk[4][2];
#pragma unroll
      for (int fj = 0; fj < 4; ++fj)
#pragma unroll
        for (int t = 0; t < 2; ++t)
          bk[fj][t] = gfrag(kb, j * 64 + fj * 16 + lr, DD, h * DH + t * 32 + g * 8);
      float pc[4] = {0.f, 0.f, 0.f, 0.f};
#pragma unroll
      for (int fi = 0; fi < 4; ++fi)
#pragma unroll
        for (int fj = 0; fj < 4; ++fj) {
          f32x4 z = {0.f, 0.f, 0.f, 0.f};
          z = mfma16(aq[fi][0], bk[fj][0], z);
          z = mfma16(aq[fi][1], bk[fj][1], z);
#pragma unroll
          for (int r = 0; r < 4; ++r) {
            float e = exp2f(z[r] * E2C);
            if (j == c && (fj * 16 + lr) > (fi * 16 + g * 4 + r)) e = 0.f;
            pc[fj] += coef[fi][r] * e;
          }
        }
#pragma unroll
      for (int fj = 0; fj < 4; ++fj) {
        float s = pc[fj];
        s += __shfl_xor(s, 16, 64);
        s += __shfl_xor(s, 32, 64);
        pc[fj] = s;
      }
      if (lane < 16) {
#pragma unroll
        for (int fj = 0; fj < 4; ++fj)
          pcs[(size_t)(h * RSEG + c) * LL + j * 64 + fj * 16 + lr] = pc[fj];
      }
    }
  } else {
    // transpose k/v per head with 512 threads: [m][h*64+d] -> T[h][d][m]
    const int xx = x - 512;
    int mt = xx >> 5, h = (xx >> 1) & 15, wch = xx & 1;
    const u16* src = wch ? vb : kb;
    u16* dst = wch ? vT : kT;
    int m = tid >> 3, d0 = (tid & 7) * 8;
    u16x8 v = *(const u16x8*)(src + (size_t)(mt * 64 + m) * DD + h * DH + d0);
    *(u16x8*)&tile[m][d0] = v;
    __syncthreads();
    int d = tid >> 3, m0 = (tid & 7) * 8;
    u16 tmp[8];
#pragma unroll
    for (int t = 0; t < 8; ++t) tmp[t] = tile[m0 + t][d];
    *(u16x8*)(dst + (size_t)(h * DH + d) * LL + mt * 64 + m0) = *(const u16x8*)tmp;
  }
}

// ---------------- scan (blocks 0..127) + terrace attention (128..639, barrier-free) -----------
__global__ __launch_bounds__(256) void k_sterr(const float* __restrict__ pcs,
                                               const float* __restrict__ mega_decays,
                                               float* __restrict__ w, float* __restrict__ wpart,
                                               const u16* __restrict__ qb,
                                               const u16* __restrict__ kb,
                                               const u16* __restrict__ vT,
                                               float* __restrict__ out_t) {
  __shared__ u16 pt[4096];  // 4 waves x 16x64 P tile (wave-private quadrants)
  __shared__ float scanred[32][4];
  const int tid = threadIdx.x, lane = tid & 63, wave = tid >> 6;
  const int lr = lane & 15, g = lane >> 4;
  const int x = blockIdx.x;
  if (x < 128) {
    int h = x >> 3, m = (x & 7) * 256 + tid;
    float mg = __expf(mega_decays[h] * 64.f);
    mg = fminf(fmaxf(mg, 0.f), 2.f);
    float carry = 0.f;
    for (int i = 0; i < RSEG; ++i) {
      size_t o = (size_t)(h * RSEG + i) * LL + m;
      w[o] = carry;
      float s = carry;
      s += __shfl_xor(s, 1, 64);
      s += __shfl_xor(s, 2, 64);
      s += __shfl_xor(s, 4, 64);
      s += __shfl_xor(s, 8, 64);
      s += __shfl_xor(s, 16, 64);
      s += __shfl_xor(s, 32, 64);
      if (lane == 0) scanred[i][wave] = s;
      float p = (m < (i + 1) * 64) ? pcs[o] : 0.f;
      carry = carry * mg + p;
    }
    __syncthreads();
    if (tid < 32) {
      wpart[x * 32 + tid] =
          scanred[tid][0] + scanred[tid][1] + scanred[tid][2] + scanred[tid][3];
    }
  } else {
    // terrace: direct global fragments; only P tile in wave-private LDS (no barriers).
    const int xx = x - 128;
    const int c = xx & 31, h = xx >> 5;
    bf16x8 aq[2];
#pragma unroll
    for (int t = 0; t < 2; ++t)
      aq[t] = gfrag(qb, c * 64 + wave * 16 + lr, DD, h * DH + t * 32 + g * 8);

    f32x4 ot[4] = {};
    float dterr[4] = {0.f, 0.f, 0.f, 0.f};
    const int j0 = (c > 0) ? c - 1 : 0;
    for (int jj = j0; jj <= c; ++jj) {
#pragma unroll
      for (int fj = 0; fj < 4; ++fj) {
        bf16x8 bk0 = gfrag(kb, jj * 64 + fj * 16 + lr, DD, h * DH + 0 * 32 + g * 8);
        bf16x8 bk1 = gfrag(kb, jj * 64 + fj * 16 + lr, DD, h * DH + 1 * 32 + g * 8);
        f32x4 z = {0.f, 0.f, 0.f, 0.f};
        z = mfma16(aq[0], bk0, z);
        z = mfma16(aq[1], bk1, z);
#pragma unroll
        for (int r = 0; r < 4; ++r) {
          float e = exp2f(z[r] * E2C);
          if (jj == c && (fj * 16 + lr) > (wave * 16 + g * 4 + r)) e = 0.f;
          int col = fj * 16 + lr, rowb = g * 4 + r;
          *(u16*)((char*)pt + wave * 2048 + (col >> 3) * 256 + rowb * 16 + (col & 7) * 2) = f2bf(e);
          dterr[r] += e;
        }
      }
      // same-wave DS ops are in-order: read back our own quadrant without a barrier
#pragma unroll
      for (int t = 0; t < 2; ++t) {
        bf16x8 ap = frag64(pt, wave, t, lane);
#pragma unroll
        for (int f = 0; f < 4; ++f) {
          bf16x8 bv = *(const bf16x8*)(vT + (size_t)(h * DH + f * 16 + lr) * LL + jj * 64 +
                                       t * 32 + g * 8);
          ot[f] = mfma16(ap, bv, ot[f]);
        }
      }
    }
    float invdt[4];
#pragma unroll
    for (int r = 0; r < 4; ++r) {
      float s = dterr[r];
      s += __shfl_xor(s, 1, 64);
      s += __shfl_xor(s, 2, 64);
      s += __shfl_xor(s, 4, 64);
      s += __shfl_xor(s, 8, 64);
      invdt[r] = 1.f / s;
    }
#pragma unroll
    for (int f = 0; f < 4; ++f)
#pragma unroll
      for (int r = 0; r < 4; ++r) {
        int srow = wave * 16 + g * 4 + r, e = f * 16 + lr;
        out_t[((size_t)(h * RSEG + c) * 64 + srow) * 64 + e] = ot[f][r] * invdt[r];
      }
  }
}

// ---------------- kv state (4-way j-split, LDS-staged, bf16 partials) ----------------
// grid 4(sp) * 32(c) * 16(h) = 2048 blocks (h = x>>7).
__global__ __launch_bounds__(256) void k_kv(const u16* __restrict__ kT, const u16* __restrict__ vT,
                                            const float* __restrict__ w,
                                            const float* __restrict__ wpart,
                                            u16* __restrict__ kvp0, u16* __restrict__ kvp1,
                                            u16* __restrict__ kvp2, u16* __restrict__ kvp3) {
  __shared__ u16 kt[64 * 64];
  __shared__ u16 vt[64 * 64];
  __shared__ float wn[64];
  __shared__ float kvt[64 * 65];
  const int tid = threadIdx.x, lane = tid & 63, wave = tid >> 6;
  const int lr = lane & 15, g = lane >> 4;
  const int x = blockIdx.x;
  const int sp = x & 3, c = (x >> 2) & 31, h = x >> 7;
  const int n = c, base = n >> 2, rem = n & 3;
  const int lo = sp * base + (sp < rem ? sp : rem);
  const int cnt = base + (sp < rem ? 1 : 0);
  float ssum = 1e-5f;
#pragma unroll
  for (int b = 0; b < 8; ++b) ssum += wpart[(h * 8 + b) * 32 + c];
  const float invw = 1.f / ssum;
  f32x4 acc[4] = {};
  for (int t = 0; t < cnt; ++t) {
    int j = lo + t;
    __syncthreads();
    stage64(kT + (size_t)(h * DH) * LL + j * 64, LL, kt, wave, lane);
    stage64(vT + (size_t)(h * DH) * LL + j * 64, LL, vt, wave, lane);
    if (tid < 64) wn[tid] = w[(size_t)(h * RSEG + c) * LL + j * 64 + tid] * invw;
    __syncthreads();
#pragma unroll
    for (int t2 = 0; t2 < 2; ++t2) {
      bf16x8 raw = frag64(kt, wave, t2, lane);
      bf16x8 a;
      int m0 = t2 * 32 + g * 8;
#pragma unroll
      for (int i = 0; i < 8; ++i) a[i] = (__bf16)((float)raw[i] * wn[m0 + i]);
#pragma unroll
      for (int f = 0; f < 4; ++f) acc[f] = mfma16(a, frag64(vt, f, t2, lane), acc[f]);
    }
  }
  __syncthreads();
#pragma unroll
  for (int f = 0; f < 4; ++f)
#pragma unroll
    for (int r = 0; r < 4; ++r) kvt[(f * 16 + lr) * 65 + wave * 16 + g * 4 + r] = acc[f][r];
  __syncthreads();
  {
    int e = tid >> 2, d0 = (tid & 3) * 16;
    u16 tmp[16];
#pragma unroll
    for (int i = 0; i < 16; ++i) tmp[i] = f2bf(kvt[e * 65 + d0 + i]);
    u16* kvp = (sp == 0) ? kvp0 : (sp == 1) ? kvp1 : (sp == 2) ? kvp2 : kvp3;
    u16* dst = kvp + ((size_t)(h * 32 + c) * 64 + e) * 64 + d0;
    *(u16x8*)dst = *(const u16x8*)tmp;
    *(u16x8*)(dst + 8) = *(const u16x8*)(tmp + 8);
  }
}

// ---------------- out_lin + mix -> y (bf16) ----------------
__global__ __launch_bounds__(256) void k_outlin(const u16* __restrict__ qb,
                                                const u16* __restrict__ kvp0,
                                                const u16* __restrict__ kvp1,
                                                const u16* __restrict__ kvp2,
                                                const u16* __restrict__ kvp3,
                                                const float* __restrict__ out_t,
                                                const float* __restrict__ tmix,
                                                u16* __restrict__ yb) {
  const int tid = threadIdx.x, lane = tid & 63, wave = tid >> 6;
  const int lr = lane & 15, g = lane >> 4;
  const int c = blockIdx.x & 31, h = blockIdx.x >> 5;
  bf16x8 aq[2], bk[4][2];
#pragma unroll
  for (int t = 0; t < 2; ++t)
    aq[t] = *(const bf16x8*)(qb + (size_t)(c * 64 + wave * 16 + lr) * DD + h * DH + t * 32 + g * 8);
#pragma unroll
  for (int f = 0; f < 4; ++f)
#pragma unroll
    for (int t = 0; t < 2; ++t) {
      size_t off = ((size_t)(h * 32 + c) * 64 + f * 16 + lr) * 64 + t * 32 + g * 8;
      u16x8 p0 = *(const u16x8*)(kvp0 + off);
      u16x8 p1 = *(const u16x8*)(kvp1 + off);
      u16x8 p2 = *(const u16x8*)(kvp2 + off);
      u16x8 p3 = *(const u16x8*)(kvp3 + off);
      bf16x8 fr;
#pragma unroll
      for (int i = 0; i < 8; ++i)
        fr[i] = (__bf16)((bf2f(p0[i]) + bf2f(p1[i])) + (bf2f(p2[i]) + bf2f(p3[i])));
      bk[f][t] = fr;
    }
  f32x4 ao[4] = {};
#pragma unroll
  for (int t = 0; t < 2; ++t)
#pragma unroll
    for (int f = 0; f < 4; ++f) ao[f] = mfma16(aq[t], bk[f][t], ao[f]);
  float tw[4];
#pragma unroll
  for (int r = 0; r < 4; ++r) tw[r] = 1.f / (1.f + __expf(-tmix[wave * 16 + g * 4 + r]));
#pragma unroll
  for (int f = 0; f < 4; ++f)
#pragma unroll
    for (int r = 0; r < 4; ++r) {
      int s = wave * 16 + g * 4 + r, e = f * 16 + lr;
      float otv = out_t[((size_t)(h * RSEG + c) * 64 + s) * 64 + e];
      float yv = tw[r] * otv + (1.f - tw[r]) * ao[f][r];
      yb[(size_t)(c * 64 + s) * DD + h * DH + e] = f2bf(yv);
    }
}

// ---------------- host launch ----------------
extern "C" void kernel_launch(void* const* d_in, const int* in_sizes, int n_in, void* d_out,
                              int out_size, void* d_ws, size_t ws_size, hipStream_t stream) {
  const float* hs = (const float*)d_in[0];
  const float* Wq = (const float*)d_in[1];
  const float* Wk = (const float*)d_in[2];
  const float* Wv = (const float*)d_in[3];
  const float* Wc = (const float*)d_in[4];
  const float* tmix = (const float*)d_in[5];
  const float* idx_dec = (const float*)d_in[6];
  const float* mega = (const float*)d_in[7];
  char* ws = (char*)d_ws;

  // workspace layout (bytes), max offset 48234496:
  u16* hs_bf = (u16*)(ws + 0);                 // 4 MB   [dead after QKV gemm]
  u16* wq_bf = (u16*)(ws + 4194304);           // 6 MB   [dead after QKV gemm]
  float* wpart = (float*)(ws + 11010048);      // 16 KB  [k_sterr -> k_kv]
  u16* wc_bf = (u16*)(ws + 12582912);          // 2 MB   [until final gemm]
  u16* q_bf = (u16*)(ws + 14680064);           // 4 MB   [until k_outlin]
  u16* k_bf = q_bf + (size_t)LL * DD;          // 4 MB   [dead after k_sterr] -> kvp1
  u16* v_bf = q_bf + 2 * (size_t)LL * DD;      // 4 MB   [dead after transpose] -> kvp0
  u16* kT = (u16*)(ws + 27262976);             // 4 MB
  u16* vT = (u16*)(ws + 31457280);             // 4 MB
  float* pcs = (float*)(ws + 35651584);        // 4 MB   [dead after k_sterr scan] -> kvp2
  float* wbuf = (float*)(ws + 39845888);       // 4 MB
  u16* kvp3 = (u16*)(ws + 44040192);           // 4 MB
  float* out_t = (float*)(ws + 0);             // 8 MB (reuses hs_bf + Wq/Wk region)
  u16* y_bf = (u16*)(ws + 8388608);            // 4 MB (reuses Wv tail + wpart region; written by
                                               //       k_outlin AFTER k_kv's wpart reads)
  u16* kvp0 = v_bf;
  u16* kvp1 = k_bf;
  u16* kvp2 = (u16*)pcs;

  k_castall<<<dim3(6291456 / 4 / 256), 256, 0, stream>>>(hs, Wq, Wk, Wv, Wc, hs_bf, wq_bf, wc_bf);

  // QKV GEMM: 64x64 tiles -> 1536 blocks (6 blocks/CU) for better latency hiding
  k_gemm<64, 64, false><<<dim3(DD / 64, LL / 64, 3), 256, 0, stream>>>(hs_bf, wq_bf, q_bf,
                                                                       nullptr);
  // 512 score blocks (c descending, stragglers first) + 1024 transpose blocks
  k_trsc<<<dim3(1536), 512, 0, stream>>>(q_bf, k_bf, v_bf, idx_dec, pcs, kT, vT);
  k_sterr<<<dim3(640), 256, 0, stream>>>(pcs, mega, wbuf, wpart, q_bf, k_bf, vT, out_t);
  k_kv<<<dim3(2048), 256, 0, stream>>>(kT, vT, wbuf, wpart, kvp0, kvp1, kvp2, kvp3);
  k_outlin<<<dim3(512), 256, 0, stream>>>(q_bf, kvp0, kvp1, kvp2, kvp3, out_t, tmix, y_bf);
  k_gemm<64, 64, true><<<dim3(DD / 64, LL / 64, 1), 256, 0, stream>>>(y_bf, wc_bf, nullptr,
                                                                      (float*)d_out);
  (void)in_sizes; (void)n_in; (void)out_size; (void)ws_size;
}

// Round 15
// 165.994 us; speedup vs baseline: 1.0636x; 1.0636x over previous
//
#include <hip/hip_runtime.h>
#include <cstdint>
#include <cstddef>

// Problem constants (b=1)
#define LL 2048     // sequence length
#define DD 1024     // model dim
#define NH 16       // heads
#define DH 64       // head dim
#define RSEG 32     // LL/64 chunks

#define E2C 0.18033688f  // 0.125 * log2(e): exp(z/8) = exp2(z*E2C)

using u16 = unsigned short;
typedef __attribute__((ext_vector_type(8))) __bf16 bf16x8;
typedef __attribute__((ext_vector_type(4))) float f32x4;
typedef __attribute__((ext_vector_type(8))) u16 u16x8;
typedef __attribute__((ext_vector_type(4))) u16 u16x4;
typedef __attribute__((ext_vector_type(4))) float f32x4v;

static __device__ __forceinline__ u16 f2bf(float f) {
  union { float f; unsigned u; } a; a.f = f;
  unsigned u = a.u;
  return (u16)((u + 0x7fffu + ((u >> 16) & 1u)) >> 16);
}
static __device__ __forceinline__ float bf2f(u16 x) {
  union { unsigned u; float f; } a; a.u = ((unsigned)x) << 16;
  return a.f;
}

static __device__ __forceinline__ f32x4 mfma16(bf16x8 a, bf16x8 b, f32x4 c) {
  return __builtin_amdgcn_mfma_f32_16x16x32_bf16(a, b, c, 0, 0, 0);
}

#define GLOAD_LDS16(gsrc, ldst)                                                        \
  __builtin_amdgcn_global_load_lds((const __attribute__((address_space(1))) void*)(gsrc), \
                                   (__attribute__((address_space(3))) void*)(ldst), 16, 0, 0)

// Stage a 64x64 bf16 tile from row-major global (row stride rs elems) into MFMA
// layout: byte = rb*2048 + kh*1024 + kg*256 + lr*16
static __device__ __forceinline__ void stage64(const u16* g, int rs, u16* lds, int wave, int lane) {
  int lr = lane & 15, kg = lane >> 4;
#pragma unroll
  for (int i = 0; i < 2; ++i) {
    int idx = wave * 2 + i;
    int rb = idx >> 1, kh = idx & 1;
    const u16* src = g + (size_t)(rb * 16 + lr) * rs + kh * 32 + kg * 8;
    GLOAD_LDS16(src, (char*)lds + idx * 1024);
  }
}

// Read one 16x32 A/B fragment from LDS-staged tile
static __device__ __forceinline__ bf16x8 frag64(const u16* lds, int rb, int t, int lane) {
  return *(const bf16x8*)((const char*)lds + rb * 2048 + t * 1024 + (lane >> 4) * 256 +
                          (lane & 15) * 16);
}

// Direct global fragment load (rows row.., k-slice koff..): matches 16x16x32 A/B layout
static __device__ __forceinline__ bf16x8 gfrag(const u16* g, int row, int rs, int koff) {
  return *(const bf16x8*)(g + (size_t)row * rs + koff);
}

// ---------------- fused fp32 -> bf16 cast of all inputs ----------------
__global__ __launch_bounds__(256) void k_castall(const float* __restrict__ hs,
                                                 const float* __restrict__ Wq,
                                                 const float* __restrict__ Wk,
                                                 const float* __restrict__ Wv,
                                                 const float* __restrict__ Wc,
                                                 u16* __restrict__ hs_bf, u16* __restrict__ wq_bf,
                                                 u16* __restrict__ wc_bf) {
  int i = (blockIdx.x * 256 + threadIdx.x) * 4;  // over 6M elements
  const float* src;
  u16* dst;
  int off;
  if (i < 2097152) { src = hs; dst = hs_bf; off = i; }
  else if (i < 3145728) { src = Wq; dst = wq_bf; off = i - 2097152; }
  else if (i < 4194304) { src = Wk; dst = wq_bf + 1048576; off = i - 3145728; }
  else if (i < 5242880) { src = Wv; dst = wq_bf + 2097152; off = i - 4194304; }
  else { src = Wc; dst = wc_bf; off = i - 5242880; }
  f32x4v v = *(const f32x4v*)(src + off);
  u16x4 o;
#pragma unroll
  for (int t = 0; t < 4; ++t) o[t] = f2bf(v[t]);
  *(u16x4*)(dst + off) = o;
}

// ---------------- GEMM: C[M,N] = A[M,K] * B[N,K]^T, dbuf BK=32 ----------------
template <int BM, int BN, bool WF32>
__global__ __launch_bounds__(256) void k_gemm(const u16* __restrict__ A, const u16* __restrict__ Ball,
                                              u16* __restrict__ Cb, float* __restrict__ Cf) {
  constexpr int FI = BM / 32, FJ = BN / 32;
  __shared__ u16 lA[2][BM * 32];
  __shared__ u16 lB[2][BN * 32];
  const int tid = threadIdx.x, lane = tid & 63, wave = tid >> 6;
  const int lr = lane & 15, kg = lane >> 4;
  const int wr = wave >> 1, wc = wave & 1;
  const u16* Bp = Ball + (size_t)blockIdx.z * (DD * DD);
  const int brow = blockIdx.y * BM, bcol = blockIdx.x * BN;
  f32x4 acc[FI][FJ] = {};

  auto stage = [&](int buf, int kt) {
#pragma unroll
    for (int i = 0; i < BM / 64; ++i) {
      int rb = wave * (BM / 64) + i;
      GLOAD_LDS16(A + (size_t)(brow + rb * 16 + lr) * DD + kt * 32 + kg * 8,
                  (char*)(&lA[buf][0]) + rb * 1024);
    }
#pragma unroll
    for (int i = 0; i < BN / 64; ++i) {
      int rb = wave * (BN / 64) + i;
      GLOAD_LDS16(Bp + (size_t)(bcol + rb * 16 + lr) * DD + kt * 32 + kg * 8,
                  (char*)(&lB[buf][0]) + rb * 1024);
    }
  };

  stage(0, 0);
  int cur = 0;
  for (int kt = 0; kt < DD / 32; ++kt) {
    __syncthreads();
    if (kt + 1 < DD / 32) stage(cur ^ 1, kt + 1);
    bf16x8 af[FI], bb[FJ];
#pragma unroll
    for (int f = 0; f < FI; ++f)
      af[f] = *(const bf16x8*)((const char*)(&lA[cur][0]) + (wr * FI + f) * 1024 + kg * 256 +
                               lr * 16);
#pragma unroll
    for (int f = 0; f < FJ; ++f)
      bb[f] = *(const bf16x8*)((const char*)(&lB[cur][0]) + (wc * FJ + f) * 1024 + kg * 256 +
                               lr * 16);
#pragma unroll
    for (int i = 0; i < FI; ++i)
#pragma unroll
      for (int j = 0; j < FJ; ++j) acc[i][j] = mfma16(af[i], bb[j], acc[i][j]);
    cur ^= 1;
  }
  u16* Co = Cb + (size_t)blockIdx.z * ((size_t)LL * DD);
#pragma unroll
  for (int i = 0; i < FI; ++i)
#pragma unroll
    for (int j = 0; j < FJ; ++j)
#pragma unroll
      for (int r = 0; r < 4; ++r) {
        int row = brow + (wr * FI + i) * 16 + kg * 4 + r;
        int col = bcol + (wc * FJ + j) * 16 + lr;
        if constexpr (WF32)
          Cf[(size_t)row * DD + col] = acc[i][j][r];
        else
          Co[(size_t)row * DD + col] = f2bf(acc[i][j][r]);
      }
}

// ---------------- score (blocks 0..511, c DESC) + transpose (512..1535), 512 thr ----------------
// score: c = 31-(x>>4), h = x&15 (stragglers first); 8 waves; wave w owns tiles j = w, w+8, ...
__global__ __launch_bounds__(512) void k_trsc(const u16* __restrict__ qb, const u16* __restrict__ kb,
                                              const u16* __restrict__ vb,
                                              const float* __restrict__ idx_dec,
                                              float* __restrict__ pcs, u16* __restrict__ kT,
                                              u16* __restrict__ vT) {
  __shared__ float dsum[8][64];
  __shared__ float invd_s[64];
  __shared__ u16 tile[64][72];
  const int tid = threadIdx.x;
  const int x = blockIdx.x;
  if (x < 512) {
    const int lane = tid & 63, wave = tid >> 6;
    const int lr = lane & 15, g = lane >> 4;
    const int c = 31 - (x >> 4), h = x & 15;
    bf16x8 aq[4][2];
#pragma unroll
    for (int fi = 0; fi < 4; ++fi)
#pragma unroll
      for (int t = 0; t < 2; ++t)
        aq[fi][t] = gfrag(qb, c * 64 + fi * 16 + lr, DD, h * DH + t * 32 + g * 8);

    // pass 1: row denominators
    float drow[4][4] = {};
    for (int j = wave; j <= c; j += 8) {
      bf16x8 bk[4][2];
#pragma unroll
      for (int fj = 0; fj < 4; ++fj)
#pragma unroll
        for (int t = 0; t < 2; ++t)
          bk[fj][t] = gfrag(kb, j * 64 + fj * 16 + lr, DD, h * DH + t * 32 + g * 8);
#pragma unroll
      for (int fi = 0; fi < 4; ++fi)
#pragma unroll
        for (int fj = 0; fj < 4; ++fj) {
          f32x4 z = {0.f, 0.f, 0.f, 0.f};
          z = mfma16(aq[fi][0], bk[fj][0], z);
          z = mfma16(aq[fi][1], bk[fj][1], z);
#pragma unroll
          for (int r = 0; r < 4; ++r) {
            float e = exp2f(z[r] * E2C);
            if (j == c && (fj * 16 + lr) > (fi * 16 + g * 4 + r)) e = 0.f;
            drow[fi][r] += e;
          }
        }
    }
#pragma unroll
    for (int fi = 0; fi < 4; ++fi)
#pragma unroll
      for (int r = 0; r < 4; ++r) {
        float s = drow[fi][r];
        s += __shfl_xor(s, 1, 64);
        s += __shfl_xor(s, 2, 64);
        s += __shfl_xor(s, 4, 64);
        s += __shfl_xor(s, 8, 64);
        drow[fi][r] = s;
      }
    if (lr == 0) {
#pragma unroll
      for (int fi = 0; fi < 4; ++fi)
#pragma unroll
        for (int r = 0; r < 4; ++r) dsum[wave][fi * 16 + g * 4 + r] = drow[fi][r];
    }
    __syncthreads();
    if (tid < 64) {
      float s = 0.f;
#pragma unroll
      for (int w2 = 0; w2 < 8; ++w2) s += dsum[w2][tid];
      invd_s[tid] = 1.f / s;
    }
    __syncthreads();
    float coef[4][4];
#pragma unroll
    for (int fi = 0; fi < 4; ++fi)
#pragma unroll
      for (int r = 0; r < 4; ++r) {
        int row = fi * 16 + g * 4 + r;
        coef[fi][r] = __expf(idx_dec[h * 64 + row]) * invd_s[row];
      }

    // pass 2: pcs columns
    for (int j = wave; j <= c; j += 8) {
      bf16x8 bk[4][2];
#pragma unroll
      for (int fj = 0; fj < 4; ++fj)
#pragma unroll
        for (int t = 0; t < 2; ++t)
          bk[fj][t] = gfrag(kb, j * 64 + fj * 16 + lr, DD, h * DH + t * 32 + g * 8);
      float pc[4] = {0.f, 0.f, 0.f, 0.f};
#pragma unroll
      for (int fi = 0; fi < 4; ++fi)
#pragma unroll
        for (int fj = 0; fj < 4; ++fj) {
          f32x4 z = {0.f, 0.f, 0.f, 0.f};
          z = mfma16(aq[fi][0], bk[fj][0], z);
          z = mfma16(aq[fi][1], bk[fj][1], z);
#pragma unroll
          for (int r = 0; r < 4; ++r) {
            float e = exp2f(z[r] * E2C);
            if (j == c && (fj * 16 + lr) > (fi * 16 + g * 4 + r)) e = 0.f;
            pc[fj] += coef[fi][r] * e;
          }
        }
#pragma unroll
      for (int fj = 0; fj < 4; ++fj) {
        float s = pc[fj];
        s += __shfl_xor(s, 16, 64);
        s += __shfl_xor(s, 32, 64);
        pc[fj] = s;
      }
      if (lane < 16) {
#pragma unroll
        for (int fj = 0; fj < 4; ++fj)
          pcs[(size_t)(h * RSEG + c) * LL + j * 64 + fj * 16 + lr] = pc[fj];
      }
    }
  } else {
    // transpose k/v per head with 512 threads: [m][h*64+d] -> T[h][d][m]
    const int xx = x - 512;
    int mt = xx >> 5, h = (xx >> 1) & 15, wch = xx & 1;
    const u16* src = wch ? vb : kb;
    u16* dst = wch ? vT : kT;
    int m = tid >> 3, d0 = (tid & 7) * 8;
    u16x8 v = *(const u16x8*)(src + (size_t)(mt * 64 + m) * DD + h * DH + d0);
    *(u16x8*)&tile[m][d0] = v;
    __syncthreads();
    int d = tid >> 3, m0 = (tid & 7) * 8;
    u16 tmp[8];
#pragma unroll
    for (int t = 0; t < 8; ++t) tmp[t] = tile[m0 + t][d];
    *(u16x8*)(dst + (size_t)(h * DH + d) * LL + mt * 64 + m0) = *(const u16x8*)tmp;
  }
}

// ---------------- scan (blocks 0..127) + terrace attention (128..639, barrier-free) -----------
// out_t stored as bf16 (u16) to halve intermediate traffic.
__global__ __launch_bounds__(256) void k_sterr(const float* __restrict__ pcs,
                                               const float* __restrict__ mega_decays,
                                               float* __restrict__ w, float* __restrict__ wpart,
                                               const u16* __restrict__ qb,
                                               const u16* __restrict__ kb,
                                               const u16* __restrict__ vT,
                                               u16* __restrict__ out_t) {
  __shared__ u16 pt[4096];  // 4 waves x 16x64 P tile (wave-private quadrants)
  __shared__ float scanred[32][4];
  const int tid = threadIdx.x, lane = tid & 63, wave = tid >> 6;
  const int lr = lane & 15, g = lane >> 4;
  const int x = blockIdx.x;
  if (x < 128) {
    int h = x >> 3, m = (x & 7) * 256 + tid;
    float mg = __expf(mega_decays[h] * 64.f);
    mg = fminf(fmaxf(mg, 0.f), 2.f);
    float carry = 0.f;
    for (int i = 0; i < RSEG; ++i) {
      size_t o = (size_t)(h * RSEG + i) * LL + m;
      w[o] = carry;
      float s = carry;
      s += __shfl_xor(s, 1, 64);
      s += __shfl_xor(s, 2, 64);
      s += __shfl_xor(s, 4, 64);
      s += __shfl_xor(s, 8, 64);
      s += __shfl_xor(s, 16, 64);
      s += __shfl_xor(s, 32, 64);
      if (lane == 0) scanred[i][wave] = s;
      float p = (m < (i + 1) * 64) ? pcs[o] : 0.f;
      carry = carry * mg + p;
    }
    __syncthreads();
    if (tid < 32) {
      wpart[x * 32 + tid] =
          scanred[tid][0] + scanred[tid][1] + scanred[tid][2] + scanred[tid][3];
    }
  } else {
    // terrace: direct global fragments; only P tile in wave-private LDS (no barriers).
    const int xx = x - 128;
    const int c = xx & 31, h = xx >> 5;
    bf16x8 aq[2];
#pragma unroll
    for (int t = 0; t < 2; ++t)
      aq[t] = gfrag(qb, c * 64 + wave * 16 + lr, DD, h * DH + t * 32 + g * 8);

    f32x4 ot[4] = {};
    float dterr[4] = {0.f, 0.f, 0.f, 0.f};
    const int j0 = (c > 0) ? c - 1 : 0;
    for (int jj = j0; jj <= c; ++jj) {
#pragma unroll
      for (int fj = 0; fj < 4; ++fj) {
        bf16x8 bk0 = gfrag(kb, jj * 64 + fj * 16 + lr, DD, h * DH + 0 * 32 + g * 8);
        bf16x8 bk1 = gfrag(kb, jj * 64 + fj * 16 + lr, DD, h * DH + 1 * 32 + g * 8);
        f32x4 z = {0.f, 0.f, 0.f, 0.f};
        z = mfma16(aq[0], bk0, z);
        z = mfma16(aq[1], bk1, z);
#pragma unroll
        for (int r = 0; r < 4; ++r) {
          float e = exp2f(z[r] * E2C);
          if (jj == c && (fj * 16 + lr) > (wave * 16 + g * 4 + r)) e = 0.f;
          int col = fj * 16 + lr, rowb = g * 4 + r;
          *(u16*)((char*)pt + wave * 2048 + (col >> 3) * 256 + rowb * 16 + (col & 7) * 2) = f2bf(e);
          dterr[r] += e;
        }
      }
      // same-wave DS ops are in-order: read back our own quadrant without a barrier
#pragma unroll
      for (int t = 0; t < 2; ++t) {
        bf16x8 ap = frag64(pt, wave, t, lane);
#pragma unroll
        for (int f = 0; f < 4; ++f) {
          bf16x8 bv = *(const bf16x8*)(vT + (size_t)(h * DH + f * 16 + lr) * LL + jj * 64 +
                                       t * 32 + g * 8);
          ot[f] = mfma16(ap, bv, ot[f]);
        }
      }
    }
    float invdt[4];
#pragma unroll
    for (int r = 0; r < 4; ++r) {
      float s = dterr[r];
      s += __shfl_xor(s, 1, 64);
      s += __shfl_xor(s, 2, 64);
      s += __shfl_xor(s, 4, 64);
      s += __shfl_xor(s, 8, 64);
      invdt[r] = 1.f / s;
    }
#pragma unroll
    for (int f = 0; f < 4; ++f)
#pragma unroll
      for (int r = 0; r < 4; ++r) {
        int srow = wave * 16 + g * 4 + r, e = f * 16 + lr;
        out_t[((size_t)(h * RSEG + c) * 64 + srow) * 64 + e] = f2bf(ot[f][r] * invdt[r]);
      }
  }
}

// ---------------- kv state (4-way j-split, LDS-staged, bf16 partials) ----------------
// grid 4(sp) * 32(c) * 16(h) = 2048 blocks (h = x>>7).
__global__ __launch_bounds__(256) void k_kv(const u16* __restrict__ kT, const u16* __restrict__ vT,
                                            const float* __restrict__ w,
                                            const float* __restrict__ wpart,
                                            u16* __restrict__ kvp0, u16* __restrict__ kvp1,
                                            u16* __restrict__ kvp2, u16* __restrict__ kvp3) {
  __shared__ u16 kt[64 * 64];
  __shared__ u16 vt[64 * 64];
  __shared__ float wn[64];
  __shared__ float kvt[64 * 65];
  const int tid = threadIdx.x, lane = tid & 63, wave = tid >> 6;
  const int lr = lane & 15, g = lane >> 4;
  const int x = blockIdx.x;
  const int sp = x & 3, c = (x >> 2) & 31, h = x >> 7;
  const int n = c, base = n >> 2, rem = n & 3;
  const int lo = sp * base + (sp < rem ? sp : rem);
  const int cnt = base + (sp < rem ? 1 : 0);
  float ssum = 1e-5f;
#pragma unroll
  for (int b = 0; b < 8; ++b) ssum += wpart[(h * 8 + b) * 32 + c];
  const float invw = 1.f / ssum;
  f32x4 acc[4] = {};
  for (int t = 0; t < cnt; ++t) {
    int j = lo + t;
    __syncthreads();
    stage64(kT + (size_t)(h * DH) * LL + j * 64, LL, kt, wave, lane);
    stage64(vT + (size_t)(h * DH) * LL + j * 64, LL, vt, wave, lane);
    if (tid < 64) wn[tid] = w[(size_t)(h * RSEG + c) * LL + j * 64 + tid] * invw;
    __syncthreads();
#pragma unroll
    for (int t2 = 0; t2 < 2; ++t2) {
      bf16x8 raw = frag64(kt, wave, t2, lane);
      bf16x8 a;
      int m0 = t2 * 32 + g * 8;
#pragma unroll
      for (int i = 0; i < 8; ++i) a[i] = (__bf16)((float)raw[i] * wn[m0 + i]);
#pragma unroll
      for (int f = 0; f < 4; ++f) acc[f] = mfma16(a, frag64(vt, f, t2, lane), acc[f]);
    }
  }
  __syncthreads();
#pragma unroll
  for (int f = 0; f < 4; ++f)
#pragma unroll
    for (int r = 0; r < 4; ++r) kvt[(f * 16 + lr) * 65 + wave * 16 + g * 4 + r] = acc[f][r];
  __syncthreads();
  {
    int e = tid >> 2, d0 = (tid & 3) * 16;
    u16 tmp[16];
#pragma unroll
    for (int i = 0; i < 16; ++i) tmp[i] = f2bf(kvt[e * 65 + d0 + i]);
    u16* kvp = (sp == 0) ? kvp0 : (sp == 1) ? kvp1 : (sp == 2) ? kvp2 : kvp3;
    u16* dst = kvp + ((size_t)(h * 32 + c) * 64 + e) * 64 + d0;
    *(u16x8*)dst = *(const u16x8*)tmp;
    *(u16x8*)(dst + 8) = *(const u16x8*)(tmp + 8);
  }
}

// ---------------- out_lin + mix -> y (bf16) ----------------
__global__ __launch_bounds__(256) void k_outlin(const u16* __restrict__ qb,
                                                const u16* __restrict__ kvp0,
                                                const u16* __restrict__ kvp1,
                                                const u16* __restrict__ kvp2,
                                                const u16* __restrict__ kvp3,
                                                const u16* __restrict__ out_t,
                                                const float* __restrict__ tmix,
                                                u16* __restrict__ yb) {
  const int tid = threadIdx.x, lane = tid & 63, wave = tid >> 6;
  const int lr = lane & 15, g = lane >> 4;
  const int c = blockIdx.x & 31, h = blockIdx.x >> 5;
  bf16x8 aq[2], bk[4][2];
#pragma unroll
  for (int t = 0; t < 2; ++t)
    aq[t] = *(const bf16x8*)(qb + (size_t)(c * 64 + wave * 16 + lr) * DD + h * DH + t * 32 + g * 8);
#pragma unroll
  for (int f = 0; f < 4; ++f)
#pragma unroll
    for (int t = 0; t < 2; ++t) {
      size_t off = ((size_t)(h * 32 + c) * 64 + f * 16 + lr) * 64 + t * 32 + g * 8;
      u16x8 p0 = *(const u16x8*)(kvp0 + off);
      u16x8 p1 = *(const u16x8*)(kvp1 + off);
      u16x8 p2 = *(const u16x8*)(kvp2 + off);
      u16x8 p3 = *(const u16x8*)(kvp3 + off);
      bf16x8 fr;
#pragma unroll
      for (int i = 0; i < 8; ++i)
        fr[i] = (__bf16)((bf2f(p0[i]) + bf2f(p1[i])) + (bf2f(p2[i]) + bf2f(p3[i])));
      bk[f][t] = fr;
    }
  f32x4 ao[4] = {};
#pragma unroll
  for (int t = 0; t < 2; ++t)
#pragma unroll
    for (int f = 0; f < 4; ++f) ao[f] = mfma16(aq[t], bk[f][t], ao[f]);
  float tw[4];
#pragma unroll
  for (int r = 0; r < 4; ++r) tw[r] = 1.f / (1.f + __expf(-tmix[wave * 16 + g * 4 + r]));
#pragma unroll
  for (int f = 0; f < 4; ++f)
#pragma unroll
    for (int r = 0; r < 4; ++r) {
      int s = wave * 16 + g * 4 + r, e = f * 16 + lr;
      float otv = bf2f(out_t[((size_t)(h * RSEG + c) * 64 + s) * 64 + e]);
      float yv = tw[r] * otv + (1.f - tw[r]) * ao[f][r];
      yb[(size_t)(c * 64 + s) * DD + h * DH + e] = f2bf(yv);
    }
}

// ---------------- host launch ----------------
extern "C" void kernel_launch(void* const* d_in, const int* in_sizes, int n_in, void* d_out,
                              int out_size, void* d_ws, size_t ws_size, hipStream_t stream) {
  const float* hs = (const float*)d_in[0];
  const float* Wq = (const float*)d_in[1];
  const float* Wk = (const float*)d_in[2];
  const float* Wv = (const float*)d_in[3];
  const float* Wc = (const float*)d_in[4];
  const float* tmix = (const float*)d_in[5];
  const float* idx_dec = (const float*)d_in[6];
  const float* mega = (const float*)d_in[7];
  char* ws = (char*)d_ws;

  // workspace layout (bytes), max offset 48234496:
  u16* hs_bf = (u16*)(ws + 0);                 // 4 MB   [dead after QKV gemm]
  u16* wq_bf = (u16*)(ws + 4194304);           // 6 MB   [dead after QKV gemm]
  float* wpart = (float*)(ws + 11010048);      // 16 KB  [k_sterr -> k_kv]
  u16* wc_bf = (u16*)(ws + 12582912);          // 2 MB   [until final gemm]
  u16* q_bf = (u16*)(ws + 14680064);           // 4 MB   [until k_outlin]
  u16* k_bf = q_bf + (size_t)LL * DD;          // 4 MB   [dead after k_sterr] -> kvp1
  u16* v_bf = q_bf + 2 * (size_t)LL * DD;      // 4 MB   [dead after transpose] -> kvp0
  u16* kT = (u16*)(ws + 27262976);             // 4 MB
  u16* vT = (u16*)(ws + 31457280);             // 4 MB
  float* pcs = (float*)(ws + 35651584);        // 4 MB   [dead after k_sterr scan] -> kvp2
  float* wbuf = (float*)(ws + 39845888);       // 4 MB
  u16* kvp3 = (u16*)(ws + 44040192);           // 4 MB
  u16* out_t = (u16*)(ws + 0);                 // 4 MB bf16 (reuses hs_bf region)
  u16* y_bf = (u16*)(ws + 8388608);            // 4 MB (reuses Wq/Wk tail; written by k_outlin)
  u16* kvp0 = v_bf;
  u16* kvp1 = k_bf;
  u16* kvp2 = (u16*)pcs;

  k_castall<<<dim3(6291456 / 4 / 256), 256, 0, stream>>>(hs, Wq, Wk, Wv, Wc, hs_bf, wq_bf, wc_bf);

  // QKV GEMM: 128x64 tiles (proven best: 16 MFMA per barrier, 768 blocks)
  k_gemm<128, 64, false><<<dim3(DD / 64, LL / 128, 3), 256, 0, stream>>>(hs_bf, wq_bf, q_bf,
                                                                         nullptr);
  // 512 score blocks (c descending, stragglers first) + 1024 transpose blocks
  k_trsc<<<dim3(1536), 512, 0, stream>>>(q_bf, k_bf, v_bf, idx_dec, pcs, kT, vT);
  k_sterr<<<dim3(640), 256, 0, stream>>>(pcs, mega, wbuf, wpart, q_bf, k_bf, vT, out_t);
  k_kv<<<dim3(2048), 256, 0, stream>>>(kT, vT, wbuf, wpart, kvp0, kvp1, kvp2, kvp3);
  k_outlin<<<dim3(512), 256, 0, stream>>>(q_bf, kvp0, kvp1, kvp2, kvp3, out_t, tmix, y_bf);
  k_gemm<64, 64, true><<<dim3(DD / 64, LL / 64, 1), 256, 0, stream>>>(y_bf, wc_bf, nullptr,
                                                                      (float*)d_out);
  (void)in_sizes; (void)n_in; (void)out_size; (void)ws_size;
}

// Round 16
// 163.887 us; speedup vs baseline: 1.0773x; 1.0129x over previous
//
#include <hip/hip_runtime.h>
#include <cstdint>
#include <cstddef>

// Problem constants (b=1)
#define LL 2048     // sequence length
#define DD 1024     // model dim
#define NH 16       // heads
#define DH 64       // head dim
#define RSEG 32     // LL/64 chunks

#define E2C 0.18033688f  // 0.125 * log2(e): exp(z/8) = exp2(z*E2C)

using u16 = unsigned short;
typedef __attribute__((ext_vector_type(8))) __bf16 bf16x8;
typedef __attribute__((ext_vector_type(4))) float f32x4;
typedef __attribute__((ext_vector_type(8))) u16 u16x8;
typedef __attribute__((ext_vector_type(4))) u16 u16x4;
typedef __attribute__((ext_vector_type(4))) float f32x4v;

static __device__ __forceinline__ u16 f2bf(float f) {
  union { float f; unsigned u; } a; a.f = f;
  unsigned u = a.u;
  return (u16)((u + 0x7fffu + ((u >> 16) & 1u)) >> 16);
}
static __device__ __forceinline__ float bf2f(u16 x) {
  union { unsigned u; float f; } a; a.u = ((unsigned)x) << 16;
  return a.f;
}

static __device__ __forceinline__ f32x4 mfma16(bf16x8 a, bf16x8 b, f32x4 c) {
  return __builtin_amdgcn_mfma_f32_16x16x32_bf16(a, b, c, 0, 0, 0);
}

#define GLOAD_LDS16(gsrc, ldst)                                                        \
  __builtin_amdgcn_global_load_lds((const __attribute__((address_space(1))) void*)(gsrc), \
                                   (__attribute__((address_space(3))) void*)(ldst), 16, 0, 0)

// Stage a 64x64 bf16 tile from row-major global (row stride rs elems) into MFMA
// layout: byte = rb*2048 + kh*1024 + kg*256 + lr*16
static __device__ __forceinline__ void stage64(const u16* g, int rs, u16* lds, int wave, int lane) {
  int lr = lane & 15, kg = lane >> 4;
#pragma unroll
  for (int i = 0; i < 2; ++i) {
    int idx = wave * 2 + i;
    int rb = idx >> 1, kh = idx & 1;
    const u16* src = g + (size_t)(rb * 16 + lr) * rs + kh * 32 + kg * 8;
    GLOAD_LDS16(src, (char*)lds + idx * 1024);
  }
}

// Read one 16x32 A/B fragment from LDS-staged tile
static __device__ __forceinline__ bf16x8 frag64(const u16* lds, int rb, int t, int lane) {
  return *(const bf16x8*)((const char*)lds + rb * 2048 + t * 1024 + (lane >> 4) * 256 +
                          (lane & 15) * 16);
}

// Direct global fragment load (rows row.., k-slice koff..): matches 16x16x32 A/B layout
static __device__ __forceinline__ bf16x8 gfrag(const u16* g, int row, int rs, int koff) {
  return *(const bf16x8*)(g + (size_t)row * rs + koff);
}

// ---------------- fused fp32 -> bf16 cast of all inputs ----------------
__global__ __launch_bounds__(256) void k_castall(const float* __restrict__ hs,
                                                 const float* __restrict__ Wq,
                                                 const float* __restrict__ Wk,
                                                 const float* __restrict__ Wv,
                                                 const float* __restrict__ Wc,
                                                 u16* __restrict__ hs_bf, u16* __restrict__ wq_bf,
                                                 u16* __restrict__ wc_bf) {
  int i = (blockIdx.x * 256 + threadIdx.x) * 4;  // over 6M elements
  const float* src;
  u16* dst;
  int off;
  if (i < 2097152) { src = hs; dst = hs_bf; off = i; }
  else if (i < 3145728) { src = Wq; dst = wq_bf; off = i - 2097152; }
  else if (i < 4194304) { src = Wk; dst = wq_bf + 1048576; off = i - 3145728; }
  else if (i < 5242880) { src = Wv; dst = wq_bf + 2097152; off = i - 4194304; }
  else { src = Wc; dst = wc_bf; off = i - 5242880; }
  f32x4v v = *(const f32x4v*)(src + off);
  u16x4 o;
#pragma unroll
  for (int t = 0; t < 4; ++t) o[t] = f2bf(v[t]);
  *(u16x4*)(dst + off) = o;
}

// ---------------- GEMM: C[M,N] = A[M,K] * B[N,K]^T, dbuf BK=32 ----------------
// For the QKV instantiation (!WF32, BN=64): z=1 (k) and z=2 (v) blocks ALSO emit the
// per-head transposed copy (kT/vT[h*64+d][m]) from the accumulator via an LDS transpose;
// the row-major copy of v (z=2) is skipped (no consumer).
template <int BM, int BN, bool WF32>
__global__ __launch_bounds__(256) void k_gemm(const u16* __restrict__ A, const u16* __restrict__ Ball,
                                              u16* __restrict__ Cb, float* __restrict__ Cf,
                                              u16* __restrict__ kTp, u16* __restrict__ vTp) {
  constexpr int FI = BM / 32, FJ = BN / 32;
  __shared__ u16 smem[2 * (BM + BN) * 32];
  u16* lA = smem;                 // 2 * BM * 32
  u16* lB = smem + 2 * BM * 32;   // 2 * BN * 32
  const int tid = threadIdx.x, lane = tid & 63, wave = tid >> 6;
  const int lr = lane & 15, kg = lane >> 4;
  const int wr = wave >> 1, wc = wave & 1;
  const u16* Bp = Ball + (size_t)blockIdx.z * (DD * DD);
  const int brow = blockIdx.y * BM, bcol = blockIdx.x * BN;
  f32x4 acc[FI][FJ] = {};

  auto stage = [&](int buf, int kt) {
#pragma unroll
    for (int i = 0; i < BM / 64; ++i) {
      int rb = wave * (BM / 64) + i;
      GLOAD_LDS16(A + (size_t)(brow + rb * 16 + lr) * DD + kt * 32 + kg * 8,
                  (char*)(lA + buf * BM * 32) + rb * 1024);
    }
#pragma unroll
    for (int i = 0; i < BN / 64; ++i) {
      int rb = wave * (BN / 64) + i;
      GLOAD_LDS16(Bp + (size_t)(bcol + rb * 16 + lr) * DD + kt * 32 + kg * 8,
                  (char*)(lB + buf * BN * 32) + rb * 1024);
    }
  };

  stage(0, 0);
  int cur = 0;
  for (int kt = 0; kt < DD / 32; ++kt) {
    __syncthreads();
    if (kt + 1 < DD / 32) stage(cur ^ 1, kt + 1);
    bf16x8 af[FI], bb[FJ];
#pragma unroll
    for (int f = 0; f < FI; ++f)
      af[f] = *(const bf16x8*)((const char*)(lA + cur * BM * 32) + (wr * FI + f) * 1024 +
                               kg * 256 + lr * 16);
#pragma unroll
    for (int f = 0; f < FJ; ++f)
      bb[f] = *(const bf16x8*)((const char*)(lB + cur * BN * 32) + (wc * FJ + f) * 1024 +
                               kg * 256 + lr * 16);
#pragma unroll
    for (int i = 0; i < FI; ++i)
#pragma unroll
      for (int j = 0; j < FJ; ++j) acc[i][j] = mfma16(af[i], bb[j], acc[i][j]);
    cur ^= 1;
  }
  // row-major write (skip for v: z==2 row-major has no consumer)
  if (WF32 || blockIdx.z != 2) {
    u16* Co = Cb + (size_t)blockIdx.z * ((size_t)LL * DD);
#pragma unroll
    for (int i = 0; i < FI; ++i)
#pragma unroll
      for (int j = 0; j < FJ; ++j)
#pragma unroll
        for (int r = 0; r < 4; ++r) {
          int row = brow + (wr * FI + i) * 16 + kg * 4 + r;
          int col = bcol + (wc * FJ + j) * 16 + lr;
          if constexpr (WF32)
            Cf[(size_t)row * DD + col] = acc[i][j][r];
          else
            Co[(size_t)row * DD + col] = f2bf(acc[i][j][r]);
        }
  }
  if constexpr (!WF32) {
    // transposed write for k (z==1) and v (z==2): T[h*64+d][m], h = blockIdx.x (BN=64)
    if (blockIdx.z != 0) {
      u16* dstT = (blockIdx.z == 1) ? kTp : vTp;
      u16(*tr)[136] = (u16(*)[136])smem;  // 64 x 136 u16 = 8704 <= 2*(BM+BN)*32 = 12288
      __syncthreads();                    // staging buffers fully consumed
#pragma unroll
      for (int i = 0; i < FI; ++i)
#pragma unroll
        for (int j = 0; j < FJ; ++j)
#pragma unroll
          for (int r = 0; r < 4; ++r) {
            int d = (wc * FJ + j) * 16 + lr;              // 0..63 (head-local dim)
            int m = (wr * FI + i) * 16 + kg * 4 + r;      // 0..BM-1 (row-local)
            tr[d][m] = f2bf(acc[i][j][r]);
          }
      __syncthreads();
      int d = tid >> 2, m0 = (tid & 3) * (BM / 4);
      u16* dst = dstT + (size_t)(blockIdx.x * 64 + d) * LL + brow + m0;
#pragma unroll
      for (int k8 = 0; k8 < BM / 32; ++k8)
        *(u16x8*)(dst + k8 * 8) = *(const u16x8*)&tr[d][m0 + k8 * 8];
    }
  }
}

// ---------------- score: 512 blocks, c DESC (stragglers first), 8 waves ----------------
// wave w owns tiles j = w, w+8, ...; pass1 denominators -> LDS reduce -> pass2 pcs.
__global__ __launch_bounds__(512) void k_trsc(const u16* __restrict__ qb, const u16* __restrict__ kb,
                                              const float* __restrict__ idx_dec,
                                              float* __restrict__ pcs) {
  __shared__ float dsum[8][64];
  __shared__ float invd_s[64];
  const int tid = threadIdx.x;
  const int x = blockIdx.x;
  const int lane = tid & 63, wave = tid >> 6;
  const int lr = lane & 15, g = lane >> 4;
  const int c = 31 - (x >> 4), h = x & 15;
  bf16x8 aq[4][2];
#pragma unroll
  for (int fi = 0; fi < 4; ++fi)
#pragma unroll
    for (int t = 0; t < 2; ++t)
      aq[fi][t] = gfrag(qb, c * 64 + fi * 16 + lr, DD, h * DH + t * 32 + g * 8);

  // pass 1: row denominators
  float drow[4][4] = {};
  for (int j = wave; j <= c; j += 8) {
    bf16x8 bk[4][2];
#pragma unroll
    for (int fj = 0; fj < 4; ++fj)
#pragma unroll
      for (int t = 0; t < 2; ++t)
        bk[fj][t] = gfrag(kb, j * 64 + fj * 16 + lr, DD, h * DH + t * 32 + g * 8);
#pragma unroll
    for (int fi = 0; fi < 4; ++fi)
#pragma unroll
      for (int fj = 0; fj < 4; ++fj) {
        f32x4 z = {0.f, 0.f, 0.f, 0.f};
        z = mfma16(aq[fi][0], bk[fj][0], z);
        z = mfma16(aq[fi][1], bk[fj][1], z);
#pragma unroll
        for (int r = 0; r < 4; ++r) {
          float e = exp2f(z[r] * E2C);
          if (j == c && (fj * 16 + lr) > (fi * 16 + g * 4 + r)) e = 0.f;
          drow[fi][r] += e;
        }
      }
  }
#pragma unroll
  for (int fi = 0; fi < 4; ++fi)
#pragma unroll
    for (int r = 0; r < 4; ++r) {
      float s = drow[fi][r];
      s += __shfl_xor(s, 1, 64);
      s += __shfl_xor(s, 2, 64);
      s += __shfl_xor(s, 4, 64);
      s += __shfl_xor(s, 8, 64);
      drow[fi][r] = s;
    }
  if (lr == 0) {
#pragma unroll
    for (int fi = 0; fi < 4; ++fi)
#pragma unroll
      for (int r = 0; r < 4; ++r) dsum[wave][fi * 16 + g * 4 + r] = drow[fi][r];
  }
  __syncthreads();
  if (tid < 64) {
    float s = 0.f;
#pragma unroll
    for (int w2 = 0; w2 < 8; ++w2) s += dsum[w2][tid];
    invd_s[tid] = 1.f / s;
  }
  __syncthreads();
  float coef[4][4];
#pragma unroll
  for (int fi = 0; fi < 4; ++fi)
#pragma unroll
    for (int r = 0; r < 4; ++r) {
      int row = fi * 16 + g * 4 + r;
      coef[fi][r] = __expf(idx_dec[h * 64 + row]) * invd_s[row];
    }

  // pass 2: pcs columns
  for (int j = wave; j <= c; j += 8) {
    bf16x8 bk[4][2];
#pragma unroll
    for (int fj = 0; fj < 4; ++fj)
#pragma unroll
      for (int t = 0; t < 2; ++t)
        bk[fj][t] = gfrag(kb, j * 64 + fj * 16 + lr, DD, h * DH + t * 32 + g * 8);
    float pc[4] = {0.f, 0.f, 0.f, 0.f};
#pragma unroll
    for (int fi = 0; fi < 4; ++fi)
#pragma unroll
      for (int fj = 0; fj < 4; ++fj) {
        f32x4 z = {0.f, 0.f, 0.f, 0.f};
        z = mfma16(aq[fi][0], bk[fj][0], z);
        z = mfma16(aq[fi][1], bk[fj][1], z);
#pragma unroll
        for (int r = 0; r < 4; ++r) {
          float e = exp2f(z[r] * E2C);
          if (j == c && (fj * 16 + lr) > (fi * 16 + g * 4 + r)) e = 0.f;
          pc[fj] += coef[fi][r] * e;
        }
      }
#pragma unroll
    for (int fj = 0; fj < 4; ++fj) {
      float s = pc[fj];
      s += __shfl_xor(s, 16, 64);
      s += __shfl_xor(s, 32, 64);
      pc[fj] = s;
    }
    if (lane < 16) {
#pragma unroll
      for (int fj = 0; fj < 4; ++fj)
        pcs[(size_t)(h * RSEG + c) * LL + j * 64 + fj * 16 + lr] = pc[fj];
    }
  }
}

// ---------------- scan (blocks 0..127) + terrace attention (128..639, barrier-free) -----------
// out_t stored as bf16 (u16) to halve intermediate traffic.
__global__ __launch_bounds__(256) void k_sterr(const float* __restrict__ pcs,
                                               const float* __restrict__ mega_decays,
                                               float* __restrict__ w, float* __restrict__ wpart,
                                               const u16* __restrict__ qb,
                                               const u16* __restrict__ kb,
                                               const u16* __restrict__ vT,
                                               u16* __restrict__ out_t) {
  __shared__ u16 pt[4096];  // 4 waves x 16x64 P tile (wave-private quadrants)
  __shared__ float scanred[32][4];
  const int tid = threadIdx.x, lane = tid & 63, wave = tid >> 6;
  const int lr = lane & 15, g = lane >> 4;
  const int x = blockIdx.x;
  if (x < 128) {
    int h = x >> 3, m = (x & 7) * 256 + tid;
    float mg = __expf(mega_decays[h] * 64.f);
    mg = fminf(fmaxf(mg, 0.f), 2.f);
    float carry = 0.f;
    for (int i = 0; i < RSEG; ++i) {
      size_t o = (size_t)(h * RSEG + i) * LL + m;
      w[o] = carry;
      float s = carry;
      s += __shfl_xor(s, 1, 64);
      s += __shfl_xor(s, 2, 64);
      s += __shfl_xor(s, 4, 64);
      s += __shfl_xor(s, 8, 64);
      s += __shfl_xor(s, 16, 64);
      s += __shfl_xor(s, 32, 64);
      if (lane == 0) scanred[i][wave] = s;
      float p = (m < (i + 1) * 64) ? pcs[o] : 0.f;
      carry = carry * mg + p;
    }
    __syncthreads();
    if (tid < 32) {
      wpart[x * 32 + tid] =
          scanred[tid][0] + scanred[tid][1] + scanred[tid][2] + scanred[tid][3];
    }
  } else {
    // terrace: direct global fragments; only P tile in wave-private LDS (no barriers).
    const int xx = x - 128;
    const int c = xx & 31, h = xx >> 5;
    bf16x8 aq[2];
#pragma unroll
    for (int t = 0; t < 2; ++t)
      aq[t] = gfrag(qb, c * 64 + wave * 16 + lr, DD, h * DH + t * 32 + g * 8);

    f32x4 ot[4] = {};
    float dterr[4] = {0.f, 0.f, 0.f, 0.f};
    const int j0 = (c > 0) ? c - 1 : 0;
    for (int jj = j0; jj <= c; ++jj) {
#pragma unroll
      for (int fj = 0; fj < 4; ++fj) {
        bf16x8 bk0 = gfrag(kb, jj * 64 + fj * 16 + lr, DD, h * DH + 0 * 32 + g * 8);
        bf16x8 bk1 = gfrag(kb, jj * 64 + fj * 16 + lr, DD, h * DH + 1 * 32 + g * 8);
        f32x4 z = {0.f, 0.f, 0.f, 0.f};
        z = mfma16(aq[0], bk0, z);
        z = mfma16(aq[1], bk1, z);
#pragma unroll
        for (int r = 0; r < 4; ++r) {
          float e = exp2f(z[r] * E2C);
          if (jj == c && (fj * 16 + lr) > (wave * 16 + g * 4 + r)) e = 0.f;
          int col = fj * 16 + lr, rowb = g * 4 + r;
          *(u16*)((char*)pt + wave * 2048 + (col >> 3) * 256 + rowb * 16 + (col & 7) * 2) = f2bf(e);
          dterr[r] += e;
        }
      }
      // same-wave DS ops are in-order: read back our own quadrant without a barrier
#pragma unroll
      for (int t = 0; t < 2; ++t) {
        bf16x8 ap = frag64(pt, wave, t, lane);
#pragma unroll
        for (int f = 0; f < 4; ++f) {
          bf16x8 bv = *(const bf16x8*)(vT + (size_t)(h * DH + f * 16 + lr) * LL + jj * 64 +
                                       t * 32 + g * 8);
          ot[f] = mfma16(ap, bv, ot[f]);
        }
      }
    }
    float invdt[4];
#pragma unroll
    for (int r = 0; r < 4; ++r) {
      float s = dterr[r];
      s += __shfl_xor(s, 1, 64);
      s += __shfl_xor(s, 2, 64);
      s += __shfl_xor(s, 4, 64);
      s += __shfl_xor(s, 8, 64);
      invdt[r] = 1.f / s;
    }
#pragma unroll
    for (int f = 0; f < 4; ++f)
#pragma unroll
      for (int r = 0; r < 4; ++r) {
        int srow = wave * 16 + g * 4 + r, e = f * 16 + lr;
        out_t[((size_t)(h * RSEG + c) * 64 + srow) * 64 + e] = f2bf(ot[f][r] * invdt[r]);
      }
  }
}

// ---------------- kv state (4-way j-split, LDS-staged, bf16 partials) ----------------
// grid 4(sp) * 32(c) * 16(h) = 2048 blocks (h = x>>7).
__global__ __launch_bounds__(256) void k_kv(const u16* __restrict__ kT, const u16* __restrict__ vT,
                                            const float* __restrict__ w,
                                            const float* __restrict__ wpart,
                                            u16* __restrict__ kvp0, u16* __restrict__ kvp1,
                                            u16* __restrict__ kvp2, u16* __restrict__ kvp3) {
  __shared__ u16 kt[64 * 64];
  __shared__ u16 vt[64 * 64];
  __shared__ float wn[64];
  __shared__ float kvt[64 * 65];
  const int tid = threadIdx.x, lane = tid & 63, wave = tid >> 6;
  const int lr = lane & 15, g = lane >> 4;
  const int x = blockIdx.x;
  const int sp = x & 3, c = (x >> 2) & 31, h = x >> 7;
  const int n = c, base = n >> 2, rem = n & 3;
  const int lo = sp * base + (sp < rem ? sp : rem);
  const int cnt = base + (sp < rem ? 1 : 0);
  float ssum = 1e-5f;
#pragma unroll
  for (int b = 0; b < 8; ++b) ssum += wpart[(h * 8 + b) * 32 + c];
  const float invw = 1.f / ssum;
  f32x4 acc[4] = {};
  for (int t = 0; t < cnt; ++t) {
    int j = lo + t;
    __syncthreads();
    stage64(kT + (size_t)(h * DH) * LL + j * 64, LL, kt, wave, lane);
    stage64(vT + (size_t)(h * DH) * LL + j * 64, LL, vt, wave, lane);
    if (tid < 64) wn[tid] = w[(size_t)(h * RSEG + c) * LL + j * 64 + tid] * invw;
    __syncthreads();
#pragma unroll
    for (int t2 = 0; t2 < 2; ++t2) {
      bf16x8 raw = frag64(kt, wave, t2, lane);
      bf16x8 a;
      int m0 = t2 * 32 + g * 8;
#pragma unroll
      for (int i = 0; i < 8; ++i) a[i] = (__bf16)((float)raw[i] * wn[m0 + i]);
#pragma unroll
      for (int f = 0; f < 4; ++f) acc[f] = mfma16(a, frag64(vt, f, t2, lane), acc[f]);
    }
  }
  __syncthreads();
#pragma unroll
  for (int f = 0; f < 4; ++f)
#pragma unroll
    for (int r = 0; r < 4; ++r) kvt[(f * 16 + lr) * 65 + wave * 16 + g * 4 + r] = acc[f][r];
  __syncthreads();
  {
    int e = tid >> 2, d0 = (tid & 3) * 16;
    u16 tmp[16];
#pragma unroll
    for (int i = 0; i < 16; ++i) tmp[i] = f2bf(kvt[e * 65 + d0 + i]);
    u16* kvp = (sp == 0) ? kvp0 : (sp == 1) ? kvp1 : (sp == 2) ? kvp2 : kvp3;
    u16* dst = kvp + ((size_t)(h * 32 + c) * 64 + e) * 64 + d0;
    *(u16x8*)dst = *(const u16x8*)tmp;
    *(u16x8*)(dst + 8) = *(const u16x8*)(tmp + 8);
  }
}

// ---------------- out_lin + mix -> y (bf16) ----------------
__global__ __launch_bounds__(256) void k_outlin(const u16* __restrict__ qb,
                                                const u16* __restrict__ kvp0,
                                                const u16* __restrict__ kvp1,
                                                const u16* __restrict__ kvp2,
                                                const u16* __restrict__ kvp3,
                                                const u16* __restrict__ out_t,
                                                const float* __restrict__ tmix,
                                                u16* __restrict__ yb) {
  const int tid = threadIdx.x, lane = tid & 63, wave = tid >> 6;
  const int lr = lane & 15, g = lane >> 4;
  const int c = blockIdx.x & 31, h = blockIdx.x >> 5;
  bf16x8 aq[2], bk[4][2];
#pragma unroll
  for (int t = 0; t < 2; ++t)
    aq[t] = *(const bf16x8*)(qb + (size_t)(c * 64 + wave * 16 + lr) * DD + h * DH + t * 32 + g * 8);
#pragma unroll
  for (int f = 0; f < 4; ++f)
#pragma unroll
    for (int t = 0; t < 2; ++t) {
      size_t off = ((size_t)(h * 32 + c) * 64 + f * 16 + lr) * 64 + t * 32 + g * 8;
      u16x8 p0 = *(const u16x8*)(kvp0 + off);
      u16x8 p1 = *(const u16x8*)(kvp1 + off);
      u16x8 p2 = *(const u16x8*)(kvp2 + off);
      u16x8 p3 = *(const u16x8*)(kvp3 + off);
      bf16x8 fr;
#pragma unroll
      for (int i = 0; i < 8; ++i)
        fr[i] = (__bf16)((bf2f(p0[i]) + bf2f(p1[i])) + (bf2f(p2[i]) + bf2f(p3[i])));
      bk[f][t] = fr;
    }
  f32x4 ao[4] = {};
#pragma unroll
  for (int t = 0; t < 2; ++t)
#pragma unroll
    for (int f = 0; f < 4; ++f) ao[f] = mfma16(aq[t], bk[f][t], ao[f]);
  float tw[4];
#pragma unroll
  for (int r = 0; r < 4; ++r) tw[r] = 1.f / (1.f + __expf(-tmix[wave * 16 + g * 4 + r]));
#pragma unroll
  for (int f = 0; f < 4; ++f)
#pragma unroll
    for (int r = 0; r < 4; ++r) {
      int s = wave * 16 + g * 4 + r, e = f * 16 + lr;
      float otv = bf2f(out_t[((size_t)(h * RSEG + c) * 64 + s) * 64 + e]);
      float yv = tw[r] * otv + (1.f - tw[r]) * ao[f][r];
      yb[(size_t)(c * 64 + s) * DD + h * DH + e] = f2bf(yv);
    }
}

// ---------------- host launch ----------------
extern "C" void kernel_launch(void* const* d_in, const int* in_sizes, int n_in, void* d_out,
                              int out_size, void* d_ws, size_t ws_size, hipStream_t stream) {
  const float* hs = (const float*)d_in[0];
  const float* Wq = (const float*)d_in[1];
  const float* Wk = (const float*)d_in[2];
  const float* Wv = (const float*)d_in[3];
  const float* Wc = (const float*)d_in[4];
  const float* tmix = (const float*)d_in[5];
  const float* idx_dec = (const float*)d_in[6];
  const float* mega = (const float*)d_in[7];
  char* ws = (char*)d_ws;

  // workspace layout (bytes), max offset 48234496:
  u16* hs_bf = (u16*)(ws + 0);                 // 4 MB   [dead after QKV gemm]
  u16* wq_bf = (u16*)(ws + 4194304);           // 6 MB   [dead after QKV gemm]
  float* wpart = (float*)(ws + 11010048);      // 16 KB  [k_sterr -> k_kv]
  u16* wc_bf = (u16*)(ws + 12582912);          // 2 MB   [until final gemm]
  u16* q_bf = (u16*)(ws + 14680064);           // 4 MB   [until k_outlin]
  u16* k_bf = q_bf + (size_t)LL * DD;          // 4 MB   [dead after k_sterr] -> kvp1
  u16* v_bf = q_bf + 2 * (size_t)LL * DD;      // 4 MB   [row-major v never written] -> kvp0
  u16* kT = (u16*)(ws + 27262976);             // 4 MB   [written by QKV gemm z=1]
  u16* vT = (u16*)(ws + 31457280);             // 4 MB   [written by QKV gemm z=2]
  float* pcs = (float*)(ws + 35651584);        // 4 MB   [dead after k_sterr scan] -> kvp2
  float* wbuf = (float*)(ws + 39845888);       // 4 MB
  u16* kvp3 = (u16*)(ws + 44040192);           // 4 MB
  u16* out_t = (u16*)(ws + 0);                 // 4 MB bf16 (reuses hs_bf region)
  u16* y_bf = (u16*)(ws + 8388608);            // 4 MB (reuses Wq/Wk tail; written by k_outlin)
  u16* kvp0 = v_bf;
  u16* kvp1 = k_bf;
  u16* kvp2 = (u16*)pcs;

  k_castall<<<dim3(6291456 / 4 / 256), 256, 0, stream>>>(hs, Wq, Wk, Wv, Wc, hs_bf, wq_bf, wc_bf);

  // QKV GEMM: 128x64 tiles; z=1/z=2 also emit kT/vT via LDS-transpose epilogue
  k_gemm<128, 64, false><<<dim3(DD / 64, LL / 128, 3), 256, 0, stream>>>(hs_bf, wq_bf, q_bf,
                                                                         nullptr, kT, vT);
  // 512 score blocks (c descending, stragglers first)
  k_trsc<<<dim3(512), 512, 0, stream>>>(q_bf, k_bf, idx_dec, pcs);
  k_sterr<<<dim3(640), 256, 0, stream>>>(pcs, mega, wbuf, wpart, q_bf, k_bf, vT, out_t);
  k_kv<<<dim3(2048), 256, 0, stream>>>(kT, vT, wbuf, wpart, kvp0, kvp1, kvp2, kvp3);
  k_outlin<<<dim3(512), 256, 0, stream>>>(q_bf, kvp0, kvp1, kvp2, kvp3, out_t, tmix, y_bf);
  k_gemm<64, 64, true><<<dim3(DD / 64, LL / 64, 1), 256, 0, stream>>>(y_bf, wc_bf, nullptr,
                                                                      (float*)d_out, nullptr,
                                                                      nullptr);
  (void)in_sizes; (void)n_in; (void)out_size; (void)ws_size;
}

// Round 17
// 158.597 us; speedup vs baseline: 1.1132x; 1.0334x over previous
//
#include <hip/hip_runtime.h>
#include <cstdint>
#include <cstddef>

// Problem constants (b=1)
#define LL 2048     // sequence length
#define DD 1024     // model dim
#define NH 16       // heads
#define DH 64       // head dim
#define RSEG 32     // LL/64 chunks

#define E2C 0.18033688f  // 0.125 * log2(e): exp(z/8) = exp2(z*E2C)

using u16 = unsigned short;
typedef __attribute__((ext_vector_type(8))) __bf16 bf16x8;
typedef __attribute__((ext_vector_type(4))) float f32x4;
typedef __attribute__((ext_vector_type(8))) u16 u16x8;
typedef __attribute__((ext_vector_type(4))) u16 u16x4;
typedef __attribute__((ext_vector_type(4))) float f32x4v;

static __device__ __forceinline__ u16 f2bf(float f) {
  union { float f; unsigned u; } a; a.f = f;
  unsigned u = a.u;
  return (u16)((u + 0x7fffu + ((u >> 16) & 1u)) >> 16);
}
static __device__ __forceinline__ float bf2f(u16 x) {
  union { unsigned u; float f; } a; a.u = ((unsigned)x) << 16;
  return a.f;
}

static __device__ __forceinline__ f32x4 mfma16(bf16x8 a, bf16x8 b, f32x4 c) {
  return __builtin_amdgcn_mfma_f32_16x16x32_bf16(a, b, c, 0, 0, 0);
}

#define GLOAD_LDS16(gsrc, ldst)                                                        \
  __builtin_amdgcn_global_load_lds((const __attribute__((address_space(1))) void*)(gsrc), \
                                   (__attribute__((address_space(3))) void*)(ldst), 16, 0, 0)

// Stage a 64x64 bf16 tile from row-major global (row stride rs elems) into MFMA
// layout: byte = rb*2048 + kh*1024 + kg*256 + lr*16
static __device__ __forceinline__ void stage64(const u16* g, int rs, u16* lds, int wave, int lane) {
  int lr = lane & 15, kg = lane >> 4;
#pragma unroll
  for (int i = 0; i < 2; ++i) {
    int idx = wave * 2 + i;
    int rb = idx >> 1, kh = idx & 1;
    const u16* src = g + (size_t)(rb * 16 + lr) * rs + kh * 32 + kg * 8;
    GLOAD_LDS16(src, (char*)lds + idx * 1024);
  }
}

// Read one 16x32 A/B fragment from LDS-staged tile
static __device__ __forceinline__ bf16x8 frag64(const u16* lds, int rb, int t, int lane) {
  return *(const bf16x8*)((const char*)lds + rb * 2048 + t * 1024 + (lane >> 4) * 256 +
                          (lane & 15) * 16);
}

// Direct global fragment load (rows row.., k-slice koff..): matches 16x16x32 A/B layout
static __device__ __forceinline__ bf16x8 gfrag(const u16* g, int row, int rs, int koff) {
  return *(const bf16x8*)(g + (size_t)row * rs + koff);
}

// ---------------- fused fp32 -> bf16 cast of all inputs ----------------
__global__ __launch_bounds__(256) void k_castall(const float* __restrict__ hs,
                                                 const float* __restrict__ Wq,
                                                 const float* __restrict__ Wk,
                                                 const float* __restrict__ Wv,
                                                 const float* __restrict__ Wc,
                                                 u16* __restrict__ hs_bf, u16* __restrict__ wq_bf,
                                                 u16* __restrict__ wc_bf) {
  int i = (blockIdx.x * 256 + threadIdx.x) * 4;  // over 6M elements
  const float* src;
  u16* dst;
  int off;
  if (i < 2097152) { src = hs; dst = hs_bf; off = i; }
  else if (i < 3145728) { src = Wq; dst = wq_bf; off = i - 2097152; }
  else if (i < 4194304) { src = Wk; dst = wq_bf + 1048576; off = i - 3145728; }
  else if (i < 5242880) { src = Wv; dst = wq_bf + 2097152; off = i - 4194304; }
  else { src = Wc; dst = wc_bf; off = i - 5242880; }
  f32x4v v = *(const f32x4v*)(src + off);
  u16x4 o;
#pragma unroll
  for (int t = 0; t < 4; ++t) o[t] = f2bf(v[t]);
  *(u16x4*)(dst + off) = o;
}

// ---------------- GEMM: C[M,N] = A[M,K] * B[N,K]^T, dbuf BK=32 ----------------
// For the QKV instantiation (!WF32): z=1 (k) and z=2 (v) blocks ALSO emit the transposed
// copy (T[col][m]) from the accumulator via an LDS transpose in 64-column halves; the
// row-major copy of v (z=2) is skipped (no consumer).
template <int BM, int BN, bool WF32>
__global__ __launch_bounds__(256) void k_gemm(const u16* __restrict__ A, const u16* __restrict__ Ball,
                                              u16* __restrict__ Cb, float* __restrict__ Cf,
                                              u16* __restrict__ kTp, u16* __restrict__ vTp) {
  constexpr int FI = BM / 32, FJ = BN / 32;
  __shared__ u16 smem[2 * (BM + BN) * 32];
  u16* lA = smem;                 // 2 * BM * 32
  u16* lB = smem + 2 * BM * 32;   // 2 * BN * 32
  const int tid = threadIdx.x, lane = tid & 63, wave = tid >> 6;
  const int lr = lane & 15, kg = lane >> 4;
  const int wr = wave >> 1, wc = wave & 1;
  const u16* Bp = Ball + (size_t)blockIdx.z * (DD * DD);
  const int brow = blockIdx.y * BM, bcol = blockIdx.x * BN;
  f32x4 acc[FI][FJ] = {};

  auto stage = [&](int buf, int kt) {
#pragma unroll
    for (int i = 0; i < BM / 64; ++i) {
      int rb = wave * (BM / 64) + i;
      GLOAD_LDS16(A + (size_t)(brow + rb * 16 + lr) * DD + kt * 32 + kg * 8,
                  (char*)(lA + buf * BM * 32) + rb * 1024);
    }
#pragma unroll
    for (int i = 0; i < BN / 64; ++i) {
      int rb = wave * (BN / 64) + i;
      GLOAD_LDS16(Bp + (size_t)(bcol + rb * 16 + lr) * DD + kt * 32 + kg * 8,
                  (char*)(lB + buf * BN * 32) + rb * 1024);
    }
  };

  stage(0, 0);
  int cur = 0;
  for (int kt = 0; kt < DD / 32; ++kt) {
    __syncthreads();
    if (kt + 1 < DD / 32) stage(cur ^ 1, kt + 1);
    bf16x8 af[FI], bb[FJ];
#pragma unroll
    for (int f = 0; f < FI; ++f)
      af[f] = *(const bf16x8*)((const char*)(lA + cur * BM * 32) + (wr * FI + f) * 1024 +
                               kg * 256 + lr * 16);
#pragma unroll
    for (int f = 0; f < FJ; ++f)
      bb[f] = *(const bf16x8*)((const char*)(lB + cur * BN * 32) + (wc * FJ + f) * 1024 +
                               kg * 256 + lr * 16);
#pragma unroll
    for (int i = 0; i < FI; ++i)
#pragma unroll
      for (int j = 0; j < FJ; ++j) acc[i][j] = mfma16(af[i], bb[j], acc[i][j]);
    cur ^= 1;
  }
  // row-major write (skip for v: z==2 row-major has no consumer)
  if (WF32 || blockIdx.z != 2) {
    u16* Co = Cb + (size_t)blockIdx.z * ((size_t)LL * DD);
#pragma unroll
    for (int i = 0; i < FI; ++i)
#pragma unroll
      for (int j = 0; j < FJ; ++j)
#pragma unroll
        for (int r = 0; r < 4; ++r) {
          int row = brow + (wr * FI + i) * 16 + kg * 4 + r;
          int col = bcol + (wc * FJ + j) * 16 + lr;
          if constexpr (WF32)
            Cf[(size_t)row * DD + col] = acc[i][j][r];
          else
            Co[(size_t)row * DD + col] = f2bf(acc[i][j][r]);
        }
  }
  if constexpr (!WF32) {
    // transposed write for k (z==1) and v (z==2): T[bcol+col][m], in 64-col halves
    if (blockIdx.z != 0) {
      u16* dstT = (blockIdx.z == 1) ? kTp : vTp;
      u16(*tr)[BM + 8] = (u16(*)[BM + 8])smem;  // 64 x (BM+8) u16 <= 2*(BM+BN)*32
#pragma unroll
      for (int dh = 0; dh < BN / 64; ++dh) {
        __syncthreads();  // staging / previous half's reads complete
        if (BN == 64 || wc == dh) {
#pragma unroll
          for (int i = 0; i < FI; ++i)
#pragma unroll
            for (int j = 0; j < FJ; ++j)
#pragma unroll
              for (int r = 0; r < 4; ++r) {
                int colh = (wc * FJ + j) * 16 + lr - dh * 64;  // 0..63
                int m = (wr * FI + i) * 16 + kg * 4 + r;       // 0..BM-1
                tr[colh][m] = f2bf(acc[i][j][r]);
              }
        }
        __syncthreads();
        int d = tid >> 2, m0 = (tid & 3) * (BM / 4);
        u16* dst = dstT + (size_t)(bcol + dh * 64 + d) * LL + brow + m0;
#pragma unroll
        for (int k8 = 0; k8 < BM / 32; ++k8)
          *(u16x8*)(dst + k8 * 8) = *(const u16x8*)&tr[d][m0 + k8 * 8];
      }
    }
  }
}

// ---------------- score: 512 blocks, c DESC (stragglers first), 8 waves ----------------
// wave w owns tiles j = w, w+8, ...; pass1 denominators -> LDS reduce -> pass2 pcs.
__global__ __launch_bounds__(512) void k_trsc(const u16* __restrict__ qb, const u16* __restrict__ kb,
                                              const float* __restrict__ idx_dec,
                                              float* __restrict__ pcs) {
  __shared__ float dsum[8][64];
  __shared__ float invd_s[64];
  const int tid = threadIdx.x;
  const int x = blockIdx.x;
  const int lane = tid & 63, wave = tid >> 6;
  const int lr = lane & 15, g = lane >> 4;
  const int c = 31 - (x >> 4), h = x & 15;
  bf16x8 aq[4][2];
#pragma unroll
  for (int fi = 0; fi < 4; ++fi)
#pragma unroll
    for (int t = 0; t < 2; ++t)
      aq[fi][t] = gfrag(qb, c * 64 + fi * 16 + lr, DD, h * DH + t * 32 + g * 8);

  // pass 1: row denominators
  float drow[4][4] = {};
  for (int j = wave; j <= c; j += 8) {
    bf16x8 bk[4][2];
#pragma unroll
    for (int fj = 0; fj < 4; ++fj)
#pragma unroll
      for (int t = 0; t < 2; ++t)
        bk[fj][t] = gfrag(kb, j * 64 + fj * 16 + lr, DD, h * DH + t * 32 + g * 8);
#pragma unroll
    for (int fi = 0; fi < 4; ++fi)
#pragma unroll
      for (int fj = 0; fj < 4; ++fj) {
        f32x4 z = {0.f, 0.f, 0.f, 0.f};
        z = mfma16(aq[fi][0], bk[fj][0], z);
        z = mfma16(aq[fi][1], bk[fj][1], z);
#pragma unroll
        for (int r = 0; r < 4; ++r) {
          float e = exp2f(z[r] * E2C);
          if (j == c && (fj * 16 + lr) > (fi * 16 + g * 4 + r)) e = 0.f;
          drow[fi][r] += e;
        }
      }
  }
#pragma unroll
  for (int fi = 0; fi < 4; ++fi)
#pragma unroll
    for (int r = 0; r < 4; ++r) {
      float s = drow[fi][r];
      s += __shfl_xor(s, 1, 64);
      s += __shfl_xor(s, 2, 64);
      s += __shfl_xor(s, 4, 64);
      s += __shfl_xor(s, 8, 64);
      drow[fi][r] = s;
    }
  if (lr == 0) {
#pragma unroll
    for (int fi = 0; fi < 4; ++fi)
#pragma unroll
      for (int r = 0; r < 4; ++r) dsum[wave][fi * 16 + g * 4 + r] = drow[fi][r];
  }
  __syncthreads();
  if (tid < 64) {
    float s = 0.f;
#pragma unroll
    for (int w2 = 0; w2 < 8; ++w2) s += dsum[w2][tid];
    invd_s[tid] = 1.f / s;
  }
  __syncthreads();
  float coef[4][4];
#pragma unroll
  for (int fi = 0; fi < 4; ++fi)
#pragma unroll
    for (int r = 0; r < 4; ++r) {
      int row = fi * 16 + g * 4 + r;
      coef[fi][r] = __expf(idx_dec[h * 64 + row]) * invd_s[row];
    }

  // pass 2: pcs columns
  for (int j = wave; j <= c; j += 8) {
    bf16x8 bk[4][2];
#pragma unroll
    for (int fj = 0; fj < 4; ++fj)
#pragma unroll
      for (int t = 0; t < 2; ++t)
        bk[fj][t] = gfrag(kb, j * 64 + fj * 16 + lr, DD, h * DH + t * 32 + g * 8);
    float pc[4] = {0.f, 0.f, 0.f, 0.f};
#pragma unroll
    for (int fi = 0; fi < 4; ++fi)
#pragma unroll
      for (int fj = 0; fj < 4; ++fj) {
        f32x4 z = {0.f, 0.f, 0.f, 0.f};
        z = mfma16(aq[fi][0], bk[fj][0], z);
        z = mfma16(aq[fi][1], bk[fj][1], z);
#pragma unroll
        for (int r = 0; r < 4; ++r) {
          float e = exp2f(z[r] * E2C);
          if (j == c && (fj * 16 + lr) > (fi * 16 + g * 4 + r)) e = 0.f;
          pc[fj] += coef[fi][r] * e;
        }
      }
#pragma unroll
    for (int fj = 0; fj < 4; ++fj) {
      float s = pc[fj];
      s += __shfl_xor(s, 16, 64);
      s += __shfl_xor(s, 32, 64);
      pc[fj] = s;
    }
    if (lane < 16) {
#pragma unroll
      for (int fj = 0; fj < 4; ++fj)
        pcs[(size_t)(h * RSEG + c) * LL + j * 64 + fj * 16 + lr] = pc[fj];
    }
  }
}

// ---------------- scan (blocks 0..127) + terrace attention (128..639, barrier-free) -----------
// out_t stored as bf16 (u16) to halve intermediate traffic.
__global__ __launch_bounds__(256) void k_sterr(const float* __restrict__ pcs,
                                               const float* __restrict__ mega_decays,
                                               float* __restrict__ w, float* __restrict__ wpart,
                                               const u16* __restrict__ qb,
                                               const u16* __restrict__ kb,
                                               const u16* __restrict__ vT,
                                               u16* __restrict__ out_t) {
  __shared__ u16 pt[4096];  // 4 waves x 16x64 P tile (wave-private quadrants)
  __shared__ float scanred[32][4];
  const int tid = threadIdx.x, lane = tid & 63, wave = tid >> 6;
  const int lr = lane & 15, g = lane >> 4;
  const int x = blockIdx.x;
  if (x < 128) {
    int h = x >> 3, m = (x & 7) * 256 + tid;
    float mg = __expf(mega_decays[h] * 64.f);
    mg = fminf(fmaxf(mg, 0.f), 2.f);
    float carry = 0.f;
    for (int i = 0; i < RSEG; ++i) {
      size_t o = (size_t)(h * RSEG + i) * LL + m;
      w[o] = carry;
      float s = carry;
      s += __shfl_xor(s, 1, 64);
      s += __shfl_xor(s, 2, 64);
      s += __shfl_xor(s, 4, 64);
      s += __shfl_xor(s, 8, 64);
      s += __shfl_xor(s, 16, 64);
      s += __shfl_xor(s, 32, 64);
      if (lane == 0) scanred[i][wave] = s;
      float p = (m < (i + 1) * 64) ? pcs[o] : 0.f;
      carry = carry * mg + p;
    }
    __syncthreads();
    if (tid < 32) {
      wpart[x * 32 + tid] =
          scanred[tid][0] + scanred[tid][1] + scanred[tid][2] + scanred[tid][3];
    }
  } else {
    // terrace: direct global fragments; only P tile in wave-private LDS (no barriers).
    const int xx = x - 128;
    const int c = xx & 31, h = xx >> 5;
    bf16x8 aq[2];
#pragma unroll
    for (int t = 0; t < 2; ++t)
      aq[t] = gfrag(qb, c * 64 + wave * 16 + lr, DD, h * DH + t * 32 + g * 8);

    f32x4 ot[4] = {};
    float dterr[4] = {0.f, 0.f, 0.f, 0.f};
    const int j0 = (c > 0) ? c - 1 : 0;
    for (int jj = j0; jj <= c; ++jj) {
#pragma unroll
      for (int fj = 0; fj < 4; ++fj) {
        bf16x8 bk0 = gfrag(kb, jj * 64 + fj * 16 + lr, DD, h * DH + 0 * 32 + g * 8);
        bf16x8 bk1 = gfrag(kb, jj * 64 + fj * 16 + lr, DD, h * DH + 1 * 32 + g * 8);
        f32x4 z = {0.f, 0.f, 0.f, 0.f};
        z = mfma16(aq[0], bk0, z);
        z = mfma16(aq[1], bk1, z);
#pragma unroll
        for (int r = 0; r < 4; ++r) {
          float e = exp2f(z[r] * E2C);
          if (jj == c && (fj * 16 + lr) > (wave * 16 + g * 4 + r)) e = 0.f;
          int col = fj * 16 + lr, rowb = g * 4 + r;
          *(u16*)((char*)pt + wave * 2048 + (col >> 3) * 256 + rowb * 16 + (col & 7) * 2) = f2bf(e);
          dterr[r] += e;
        }
      }
      // same-wave DS ops are in-order: read back our own quadrant without a barrier
#pragma unroll
      for (int t = 0; t < 2; ++t) {
        bf16x8 ap = frag64(pt, wave, t, lane);
#pragma unroll
        for (int f = 0; f < 4; ++f) {
          bf16x8 bv = *(const bf16x8*)(vT + (size_t)(h * DH + f * 16 + lr) * LL + jj * 64 +
                                       t * 32 + g * 8);
          ot[f] = mfma16(ap, bv, ot[f]);
        }
      }
    }
    float invdt[4];
#pragma unroll
    for (int r = 0; r < 4; ++r) {
      float s = dterr[r];
      s += __shfl_xor(s, 1, 64);
      s += __shfl_xor(s, 2, 64);
      s += __shfl_xor(s, 4, 64);
      s += __shfl_xor(s, 8, 64);
      invdt[r] = 1.f / s;
    }
#pragma unroll
    for (int f = 0; f < 4; ++f)
#pragma unroll
      for (int r = 0; r < 4; ++r) {
        int srow = wave * 16 + g * 4 + r, e = f * 16 + lr;
        out_t[((size_t)(h * RSEG + c) * 64 + srow) * 64 + e] = f2bf(ot[f][r] * invdt[r]);
      }
  }
}

// ---------------- kv state (4-way j-split, LDS-staged, bf16 partials) ----------------
// grid 4(sp) * 32(c) * 16(h) = 2048 blocks (h = x>>7).
__global__ __launch_bounds__(256) void k_kv(const u16* __restrict__ kT, const u16* __restrict__ vT,
                                            const float* __restrict__ w,
                                            const float* __restrict__ wpart,
                                            u16* __restrict__ kvp0, u16* __restrict__ kvp1,
                                            u16* __restrict__ kvp2, u16* __restrict__ kvp3) {
  __shared__ u16 kt[64 * 64];
  __shared__ u16 vt[64 * 64];
  __shared__ float wn[64];
  __shared__ float kvt[64 * 65];
  const int tid = threadIdx.x, lane = tid & 63, wave = tid >> 6;
  const int lr = lane & 15, g = lane >> 4;
  const int x = blockIdx.x;
  const int sp = x & 3, c = (x >> 2) & 31, h = x >> 7;
  const int n = c, base = n >> 2, rem = n & 3;
  const int lo = sp * base + (sp < rem ? sp : rem);
  const int cnt = base + (sp < rem ? 1 : 0);
  float ssum = 1e-5f;
#pragma unroll
  for (int b = 0; b < 8; ++b) ssum += wpart[(h * 8 + b) * 32 + c];
  const float invw = 1.f / ssum;
  f32x4 acc[4] = {};
  for (int t = 0; t < cnt; ++t) {
    int j = lo + t;
    __syncthreads();
    stage64(kT + (size_t)(h * DH) * LL + j * 64, LL, kt, wave, lane);
    stage64(vT + (size_t)(h * DH) * LL + j * 64, LL, vt, wave, lane);
    if (tid < 64) wn[tid] = w[(size_t)(h * RSEG + c) * LL + j * 64 + tid] * invw;
    __syncthreads();
#pragma unroll
    for (int t2 = 0; t2 < 2; ++t2) {
      bf16x8 raw = frag64(kt, wave, t2, lane);
      bf16x8 a;
      int m0 = t2 * 32 + g * 8;
#pragma unroll
      for (int i = 0; i < 8; ++i) a[i] = (__bf16)((float)raw[i] * wn[m0 + i]);
#pragma unroll
      for (int f = 0; f < 4; ++f) acc[f] = mfma16(a, frag64(vt, f, t2, lane), acc[f]);
    }
  }
  __syncthreads();
#pragma unroll
  for (int f = 0; f < 4; ++f)
#pragma unroll
    for (int r = 0; r < 4; ++r) kvt[(f * 16 + lr) * 65 + wave * 16 + g * 4 + r] = acc[f][r];
  __syncthreads();
  {
    int e = tid >> 2, d0 = (tid & 3) * 16;
    u16 tmp[16];
#pragma unroll
    for (int i = 0; i < 16; ++i) tmp[i] = f2bf(kvt[e * 65 + d0 + i]);
    u16* kvp = (sp == 0) ? kvp0 : (sp == 1) ? kvp1 : (sp == 2) ? kvp2 : kvp3;
    u16* dst = kvp + ((size_t)(h * 32 + c) * 64 + e) * 64 + d0;
    *(u16x8*)dst = *(const u16x8*)tmp;
    *(u16x8*)(dst + 8) = *(const u16x8*)(tmp + 8);
  }
}

// ---------------- out_lin + mix -> y (bf16) ----------------
__global__ __launch_bounds__(256) void k_outlin(const u16* __restrict__ qb,
                                                const u16* __restrict__ kvp0,
                                                const u16* __restrict__ kvp1,
                                                const u16* __restrict__ kvp2,
                                                const u16* __restrict__ kvp3,
                                                const u16* __restrict__ out_t,
                                                const float* __restrict__ tmix,
                                                u16* __restrict__ yb) {
  const int tid = threadIdx.x, lane = tid & 63, wave = tid >> 6;
  const int lr = lane & 15, g = lane >> 4;
  const int c = blockIdx.x & 31, h = blockIdx.x >> 5;
  bf16x8 aq[2], bk[4][2];
#pragma unroll
  for (int t = 0; t < 2; ++t)
    aq[t] = *(const bf16x8*)(qb + (size_t)(c * 64 + wave * 16 + lr) * DD + h * DH + t * 32 + g * 8);
#pragma unroll
  for (int f = 0; f < 4; ++f)
#pragma unroll
    for (int t = 0; t < 2; ++t) {
      size_t off = ((size_t)(h * 32 + c) * 64 + f * 16 + lr) * 64 + t * 32 + g * 8;
      u16x8 p0 = *(const u16x8*)(kvp0 + off);
      u16x8 p1 = *(const u16x8*)(kvp1 + off);
      u16x8 p2 = *(const u16x8*)(kvp2 + off);
      u16x8 p3 = *(const u16x8*)(kvp3 + off);
      bf16x8 fr;
#pragma unroll
      for (int i = 0; i < 8; ++i)
        fr[i] = (__bf16)((bf2f(p0[i]) + bf2f(p1[i])) + (bf2f(p2[i]) + bf2f(p3[i])));
      bk[f][t] = fr;
    }
  f32x4 ao[4] = {};
#pragma unroll
  for (int t = 0; t < 2; ++t)
#pragma unroll
    for (int f = 0; f < 4; ++f) ao[f] = mfma16(aq[t], bk[f][t], ao[f]);
  float tw[4];
#pragma unroll
  for (int r = 0; r < 4; ++r) tw[r] = 1.f / (1.f + __expf(-tmix[wave * 16 + g * 4 + r]));
#pragma unroll
  for (int f = 0; f < 4; ++f)
#pragma unroll
    for (int r = 0; r < 4; ++r) {
      int s = wave * 16 + g * 4 + r, e = f * 16 + lr;
      float otv = bf2f(out_t[((size_t)(h * RSEG + c) * 64 + s) * 64 + e]);
      float yv = tw[r] * otv + (1.f - tw[r]) * ao[f][r];
      yb[(size_t)(c * 64 + s) * DD + h * DH + e] = f2bf(yv);
    }
}

// ---------------- host launch ----------------
extern "C" void kernel_launch(void* const* d_in, const int* in_sizes, int n_in, void* d_out,
                              int out_size, void* d_ws, size_t ws_size, hipStream_t stream) {
  const float* hs = (const float*)d_in[0];
  const float* Wq = (const float*)d_in[1];
  const float* Wk = (const float*)d_in[2];
  const float* Wv = (const float*)d_in[3];
  const float* Wc = (const float*)d_in[4];
  const float* tmix = (const float*)d_in[5];
  const float* idx_dec = (const float*)d_in[6];
  const float* mega = (const float*)d_in[7];
  char* ws = (char*)d_ws;

  // workspace layout (bytes), max offset 48234496:
  u16* hs_bf = (u16*)(ws + 0);                 // 4 MB   [dead after QKV gemm]
  u16* wq_bf = (u16*)(ws + 4194304);           // 6 MB   [dead after QKV gemm]
  float* wpart = (float*)(ws + 11010048);      // 16 KB  [k_sterr -> k_kv]
  u16* wc_bf = (u16*)(ws + 12582912);          // 2 MB   [until final gemm]
  u16* q_bf = (u16*)(ws + 14680064);           // 4 MB   [until k_outlin]
  u16* k_bf = q_bf + (size_t)LL * DD;          // 4 MB   [dead after k_sterr] -> kvp1
  u16* v_bf = q_bf + 2 * (size_t)LL * DD;      // 4 MB   [row-major v never written] -> kvp0
  u16* kT = (u16*)(ws + 27262976);             // 4 MB   [written by QKV gemm z=1]
  u16* vT = (u16*)(ws + 31457280);             // 4 MB   [written by QKV gemm z=2]
  float* pcs = (float*)(ws + 35651584);        // 4 MB   [dead after k_sterr scan] -> kvp2
  float* wbuf = (float*)(ws + 39845888);       // 4 MB
  u16* kvp3 = (u16*)(ws + 44040192);           // 4 MB
  u16* out_t = (u16*)(ws + 0);                 // 4 MB bf16 (reuses hs_bf region)
  u16* y_bf = (u16*)(ws + 8388608);            // 4 MB (reuses Wq/Wk tail; written by k_outlin)
  u16* kvp0 = v_bf;
  u16* kvp1 = k_bf;
  u16* kvp2 = (u16*)pcs;

  k_castall<<<dim3(6291456 / 4 / 256), 256, 0, stream>>>(hs, Wq, Wk, Wv, Wc, hs_bf, wq_bf, wc_bf);

  // QKV GEMM: 128x128 tiles (16 MFMA per barrier); z=1/z=2 also emit kT/vT via
  // two-half LDS-transpose epilogue
  k_gemm<128, 128, false><<<dim3(DD / 128, LL / 128, 3), 256, 0, stream>>>(hs_bf, wq_bf, q_bf,
                                                                           nullptr, kT, vT);
  // 512 score blocks (c descending, stragglers first)
  k_trsc<<<dim3(512), 512, 0, stream>>>(q_bf, k_bf, idx_dec, pcs);
  k_sterr<<<dim3(640), 256, 0, stream>>>(pcs, mega, wbuf, wpart, q_bf, k_bf, vT, out_t);
  k_kv<<<dim3(2048), 256, 0, stream>>>(kT, vT, wbuf, wpart, kvp0, kvp1, kvp2, kvp3);
  k_outlin<<<dim3(512), 256, 0, stream>>>(q_bf, kvp0, kvp1, kvp2, kvp3, out_t, tmix, y_bf);
  k_gemm<64, 64, true><<<dim3(DD / 64, LL / 64, 1), 256, 0, stream>>>(y_bf, wc_bf, nullptr,
                                                                      (float*)d_out, nullptr,
                                                                      nullptr);
  (void)in_sizes; (void)n_in; (void)out_size; (void)ws_size;
}